// Round 1
// 702.048 us; speedup vs baseline: 1.1180x; 1.1180x over previous
//
#include <hip/hip_runtime.h>
#include <math.h>

#define NPTS 65536
#define DIMD 256
#define KCB  4096
#define MARGIN 2.0f

// d_out float32 offsets (reference tuple order, flattened)
#define O_ZQ   0
#define O_IDX  16777216
#define O_LOSS 16842752
#define O_PERP 16842753
#define O_CS   16842754
#define O_EMAW 16846850
#define O_W    17895426

// scratch inside d_out O_ZQ region (16,777,216 floats; dead until k_zq):
#define OFF_WSW   8388608      // swizzled w bf16: 256 grp x 8 chunk x 1024 B
#define OFF_CCNT  8912896      // 65536 ints
#define OFF_CIDS  8978432      // 65536 x 16 ints
#define OFF_OFFS  10027008     // 4097 ints
#define OFF_CUR   10031232     // 4096 ints
#define OFF_ROWS  10035328     // 65536 ints
#define OFF_GMIN  10100864     // 65536 uints
// zz -> EMAW region [0,65536); wwg -> EMAW [65536,69632)  (dead before k_dw)

typedef __attribute__((ext_vector_type(8))) short short8;   // 8 bf16
typedef __attribute__((ext_vector_type(4))) float f32x4;

__device__ __forceinline__ unsigned short f2bf(float f) {   // RNE
    unsigned u = __float_as_uint(f);
    return (unsigned short)((u + 0x7FFF + ((u >> 16) & 1)) >> 16);
}
__device__ __forceinline__ unsigned encf(float f) {         // order-preserving
    unsigned u = __float_as_uint(f);
    return (u >> 31) ? ~u : (u | 0x80000000u);
}
__device__ __forceinline__ float decf(unsigned e) {
    unsigned u = (e & 0x80000000u) ? (e & 0x7fffffffu) : ~e;
    return __uint_as_float(u);
}

// ---------------- z: fp32 -> bf16 row-layout + row sum-of-squares ----------
__global__ void k_prepz(const float* __restrict__ src, unsigned* __restrict__ dst,
                        float* __restrict__ ss) {
    int l   = threadIdx.x & 63;
    int row = blockIdx.x * 4 + (threadIdx.x >> 6);
    float4 v = ((const float4*)(src + (size_t)row * DIMD))[l];
    uint2 pk = make_uint2(f2bf(v.x) | (f2bf(v.y) << 16),
                          f2bf(v.z) | (f2bf(v.w) << 16));
    ((uint2*)dst)[(size_t)row * 64 + l] = pk;
    float s = v.x*v.x + v.y*v.y + v.z*v.z + v.w*v.w;
    #pragma unroll
    for (int off = 32; off; off >>= 1) s += __shfl_down(s, off);
    if (l == 0) ss[row] = s;
}

// ---------------- w: fp32 -> bf16 B-frag-swizzled + sum-of-squares ---------
// dest layout: group g (=k>>4), chunk c (=d>>5): 1 KB block, lane l=q*16+n16
// holds B[k=g*16+n16][kdim=c*32+q*8+j], 16 B per lane.
__global__ void k_prepw(const float* __restrict__ src, unsigned* __restrict__ dst,
                        float* __restrict__ ss) {
    int l   = threadIdx.x & 63;
    int row = blockIdx.x * 4 + (threadIdx.x >> 6);
    float4 v = ((const float4*)(src + (size_t)row * DIMD))[l];
    uint2 pk = make_uint2(f2bf(v.x) | (f2bf(v.y) << 16),
                          f2bf(v.z) | (f2bf(v.w) << 16));
    int g = row >> 4, n16 = row & 15;
    int c = l >> 3, q = (l >> 1) & 3, half = l & 1;
    ((uint2*)dst)[g * 1024 + c * 128 + (q * 16 + n16) * 2 + half] = pk;
    float s = v.x*v.x + v.y*v.y + v.z*v.z + v.w*v.w;
    #pragma unroll
    for (int off = 32; off; off >>= 1) s += __shfl_down(s, off);
    if (l == 0) ss[row] = s;
}

// ============ staged coarse sweep (m97 pattern) ============
// Block = 4 waves x 64 rows = 256 rows, one K-half (2048 codes).
// B staged global->LDS (double-buffered, 4 groups = 32 KB per buffer) via
// global_load_lds (zero VGPR staging cost); buffer order staggered per block
// (phase) to decorrelate L2 channel traffic across the 512 blocks.
#define BUFG 4
#define NBUF 32   // 128 groups per half / BUFG

// ---------------- pass 0: per-row bf16-core min ----------------
__launch_bounds__(256, 2)
__global__ void k_pass0(const unsigned* __restrict__ zbf,
                        const uint4* __restrict__ wsw4,
                        const float* __restrict__ wwg,
                        unsigned* __restrict__ gmin) {
    __shared__ __align__(16) char smem[2][BUFG * 8192];
    const int t = threadIdx.x, wv = t >> 6, l = t & 63;
    const int q = l >> 4, n16 = l & 15;
    const int rb    = blockIdx.x >> 1;
    const int half  = blockIdx.x & 1;
    const int row0  = rb * 256 + wv * 64;
    const int g0    = half * 128;
    const int phase = (blockIdx.x * 7) & 31;

    union U { uint4 u; short8 s; } afr[4][8];
    #pragma unroll
    for (int s = 0; s < 4; ++s) {
        const char* zb = (const char*)zbf + ((size_t)(row0 + s * 16 + n16) << 9) + q * 16;
        #pragma unroll
        for (int c = 0; c < 8; ++c) afr[s][c].u = *(const uint4*)(zb + c * 64);
    }

    // stage buffer-slot 'which' with staggered buffer index bi (0..NBUF-1)
    auto stage = [&](int which, int bi) {
        const uint4* srcb = wsw4 + (size_t)(g0 + ((phase + bi) & 31) * BUFG) * 512;
        #pragma unroll
        for (int j = 0; j < 8; ++j) {
            int rrow = j * 4 + wv;                      // 1 KB row of the 32 KB tile
            __builtin_amdgcn_global_load_lds(
                (const __attribute__((address_space(1))) unsigned*)(srcb + rrow * 64 + l),
                (__attribute__((address_space(3))) unsigned*)(&smem[which][rrow * 1024]),
                16, 0, 0);
        }
    };

    float minv[16];
    #pragma unroll
    for (int i = 0; i < 16; ++i) minv[i] = 3.0e38f;

    stage(0, 0);
    __syncthreads();                                    // drains vmcnt(0) implicitly

    for (int b = 0; b < NBUF; ++b) {
        const int cur = b & 1;
        if (b + 1 < NBUF) stage(cur ^ 1, b + 1);        // async prefetch next tile
        const char* sbase = smem[cur];
        const int ggb = g0 + ((phase + b) & 31) * BUFG;
        #pragma unroll
        for (int g2 = 0; g2 < BUFG; ++g2) {
            f32x4 acc[4];
            #pragma unroll
            for (int s = 0; s < 4; ++s) acc[s] = (f32x4){0.f, 0.f, 0.f, 0.f};
            #pragma unroll
            for (int c = 0; c < 8; ++c) {
                U bf; bf.u = *(const uint4*)(sbase + g2 * 8192 + c * 1024 + (l << 4));
                #pragma unroll
                for (int s = 0; s < 4; ++s)
                    acc[s] = __builtin_amdgcn_mfma_f32_16x16x32_bf16(afr[s][c].s, bf.s, acc[s], 0, 0, 0);
            }
            float wwv = wwg[(ggb + g2) * 16 + n16];
            #pragma unroll
            for (int s = 0; s < 4; ++s)
                #pragma unroll
                for (int r = 0; r < 4; ++r)
                    minv[s*4+r] = fminf(minv[s*4+r], fmaf(-2.f, acc[s][r], wwv));
        }
        __syncthreads();                                // vmcnt drain + reuse fence
    }

    #pragma unroll
    for (int i = 0; i < 16; ++i) {
        float m = minv[i];
        #pragma unroll
        for (int msk = 1; msk < 16; msk <<= 1) m = fminf(m, __shfl_xor(m, msk));
        if (n16 == 0)
            atomicMin(&gmin[row0 + (i >> 2) * 16 + q * 4 + (i & 3)], encf(m));
    }
}

// ---------------- pass 1: emit margin candidates ----------------
__launch_bounds__(256, 2)
__global__ void k_pass1(const unsigned* __restrict__ zbf,
                        const uint4* __restrict__ wsw4,
                        const float* __restrict__ wwg,
                        const unsigned* __restrict__ gmin,
                        int* __restrict__ ccnt,
                        int* __restrict__ cids) {
    __shared__ __align__(16) char smem[2][BUFG * 8192];
    const int t = threadIdx.x, wv = t >> 6, l = t & 63;
    const int q = l >> 4, n16 = l & 15;
    const int rb    = blockIdx.x >> 1;
    const int half  = blockIdx.x & 1;
    const int row0  = rb * 256 + wv * 64;
    const int g0    = half * 128;
    const int phase = (blockIdx.x * 7) & 31;

    union U { uint4 u; short8 s; } afr[4][8];
    #pragma unroll
    for (int s = 0; s < 4; ++s) {
        const char* zb = (const char*)zbf + ((size_t)(row0 + s * 16 + n16) << 9) + q * 16;
        #pragma unroll
        for (int c = 0; c < 8; ++c) afr[s][c].u = *(const uint4*)(zb + c * 64);
    }

    auto stage = [&](int which, int bi) {
        const uint4* srcb = wsw4 + (size_t)(g0 + ((phase + bi) & 31) * BUFG) * 512;
        #pragma unroll
        for (int j = 0; j < 8; ++j) {
            int rrow = j * 4 + wv;
            __builtin_amdgcn_global_load_lds(
                (const __attribute__((address_space(1))) unsigned*)(srcb + rrow * 64 + l),
                (__attribute__((address_space(3))) unsigned*)(&smem[which][rrow * 1024]),
                16, 0, 0);
        }
    };

    float thr[16];
    #pragma unroll
    for (int i = 0; i < 16; ++i)
        thr[i] = decf(gmin[row0 + (i >> 2) * 16 + q * 4 + (i & 3)]) + MARGIN;

    stage(0, 0);
    __syncthreads();

    for (int b = 0; b < NBUF; ++b) {
        const int cur = b & 1;
        if (b + 1 < NBUF) stage(cur ^ 1, b + 1);
        const char* sbase = smem[cur];
        const int ggb = g0 + ((phase + b) & 31) * BUFG;
        #pragma unroll
        for (int g2 = 0; g2 < BUFG; ++g2) {
            f32x4 acc[4];
            #pragma unroll
            for (int s = 0; s < 4; ++s) acc[s] = (f32x4){0.f, 0.f, 0.f, 0.f};
            #pragma unroll
            for (int c = 0; c < 8; ++c) {
                U bf; bf.u = *(const uint4*)(sbase + g2 * 8192 + c * 1024 + (l << 4));
                #pragma unroll
                for (int s = 0; s < 4; ++s)
                    acc[s] = __builtin_amdgcn_mfma_f32_16x16x32_bf16(afr[s][c].s, bf.s, acc[s], 0, 0, 0);
            }
            const int gg = ggb + g2;
            float wwv = wwg[gg * 16 + n16];
            #pragma unroll
            for (int s = 0; s < 4; ++s)
                #pragma unroll
                for (int r = 0; r < 4; ++r) {
                    float core = fmaf(-2.f, acc[s][r], wwv);
                    if (core <= thr[s*4+r]) {
                        int row = row0 + s * 16 + q * 4 + r;
                        int pos = atomicAdd(&ccnt[row], 1);
                        if (pos < 16) cids[row * 16 + pos] = gg * 16 + n16;
                    }
                }
        }
        __syncthreads();
    }
}

// ---------------- fp32 rescore of candidates ----------------
__global__ void k_refine(const float* __restrict__ z,
                         const float* __restrict__ w,
                         const float* __restrict__ zz,
                         const float* __restrict__ wwg,
                         const int* __restrict__ ccnt,
                         const int* __restrict__ cids,
                         float* __restrict__ counts,
                         int*   __restrict__ idxi,
                         float* __restrict__ idxf) {
    int l   = threadIdx.x & 63;
    int row = blockIdx.x * 4 + (threadIdx.x >> 6);
    int n = ccnt[row]; if (n > 16) n = 16;
    float4 zv = ((const float4*)(z + (size_t)row * DIMD))[l];
    float zzv = zz[row];
    float bd = 3.0e38f; int bi = 0x7fffffff;
    for (int j = 0; j < n; ++j) {
        int k = cids[row * 16 + j];
        float4 wv = ((const float4*)(w + (size_t)k * DIMD))[l];
        float s = zv.x*wv.x + zv.y*wv.y + zv.z*wv.z + zv.w*wv.w;
        #pragma unroll
        for (int off = 32; off; off >>= 1) s += __shfl_xor(s, off);
        float d = (zzv + wwg[k]) - 2.0f * s;
        if (d < bd || (d == bd && k < bi)) { bd = d; bi = k; }
    }
    if (l == 0) {
        idxi[row] = bi;
        idxf[row] = (float)bi;
        atomicAdd(&counts[bi], 1.0f);
    }
}

// ---------------- exclusive prefix sum of counts -> offs, cursor ----------
__global__ void k_offsets(const float* __restrict__ counts,
                          int* __restrict__ offs, int* __restrict__ cursor) {
    __shared__ int sc[1024];
    int t = threadIdx.x;
    int c[4]; int s = 0;
    #pragma unroll
    for (int i = 0; i < 4; ++i) { c[i] = (int)counts[t * 4 + i]; s += c[i]; }
    sc[t] = s;
    __syncthreads();
    for (int d = 1; d < 1024; d <<= 1) {
        int v = (t >= d) ? sc[t - d] : 0;
        __syncthreads();
        sc[t] += v;
        __syncthreads();
    }
    int o = sc[t] - s;
    #pragma unroll
    for (int i = 0; i < 4; ++i) { offs[t*4+i] = o; cursor[t*4+i] = o; o += c[i]; }
    if (t == 1023) offs[4096] = sc[1023];
}

// ---------------- fill inverted row lists ----------------
__global__ void k_fill(const int* __restrict__ idxi, int* __restrict__ cursor,
                       int* __restrict__ rows) {
    int r = blockIdx.x * 256 + threadIdx.x;
    int k = idxi[r];
    int pos = atomicAdd(&cursor[k], 1);
    rows[pos] = r;
}

// ---------------- dw[k,:] = sum of z rows assigned to k -------------------
// 256 thr: 4 row-slots x 64 d-lanes (4x parallel over the cluster).
__global__ void k_dw(const float* __restrict__ z, const int* __restrict__ offs,
                     const int* __restrict__ rows, float* __restrict__ dw) {
    __shared__ float4 part[4][64];
    int k = blockIdx.x;
    int l = threadIdx.x & 63, j = threadIdx.x >> 6;
    int o0 = offs[k], o1 = offs[k + 1];
    float4 a = make_float4(0.f, 0.f, 0.f, 0.f);
    for (int i = o0 + j; i < o1; i += 4) {
        int r = rows[i];
        float4 v = ((const float4*)(z + (size_t)r * DIMD))[l];
        a.x += v.x; a.y += v.y; a.z += v.z; a.w += v.w;
    }
    part[j][l] = a;
    __syncthreads();
    if (j == 0) {
        float4 b = part[0][l], c = part[1][l], d = part[2][l], e = part[3][l];
        a = make_float4(b.x+c.x+d.x+e.x, b.y+c.y+d.y+e.y,
                        b.z+c.z+d.z+e.z, b.w+c.w+d.w+e.w);
        ((float4*)(dw + (size_t)k * DIMD))[l] = a;
    }
}

// ---------------- cluster-size EMA + perplexity ----------------
__global__ void k_cs(const float* __restrict__ ema_cs,
                     float* __restrict__ cs_io,
                     float* __restrict__ perp) {
    __shared__ float2 red[16];
    int t = threadIdx.x;
    float csd[4];
    float nl = 0.f, el = 0.f;
    #pragma unroll
    for (int i = 0; i < 4; ++i) {
        int k = t * 4 + i;
        float c  = cs_io[k];
        float cd = ema_cs[k] * 0.99f + 0.01f * c;
        csd[i] = cd;
        nl += cd;
        float p = c * (1.0f / 65536.0f);
        el += p * logf(p + 1e-10f);
    }
    #pragma unroll
    for (int off = 32; off; off >>= 1) { nl += __shfl_down(nl, off); el += __shfl_down(el, off); }
    if ((t & 63) == 0) red[t >> 6] = make_float2(nl, el);
    __syncthreads();
    if (t == 0) {
        float n = 0.f, e = 0.f;
        for (int i = 0; i < 16; ++i) { n += red[i].x; e += red[i].y; }
        red[0] = make_float2(n, e);
        perp[0] = expf(-e);
    }
    __syncthreads();
    float n = red[0].x;
    float scale = n / (n + 4096.0f * 1e-5f);
    #pragma unroll
    for (int i = 0; i < 4; ++i)
        cs_io[t * 4 + i] = (csd[i] + 1e-5f) * scale;
}

// ---------------- new_ema_w (in-place over dw) + new_weight ----------------
__global__ void k_emaw(const float* __restrict__ ema_w,
                       const float* __restrict__ cs,
                       float* __restrict__ emaw_io,
                       float* __restrict__ wout) {
    int i = (blockIdx.x * 256 + threadIdx.x) * 4;
    int k = i >> 8;
    float4 dv = *(const float4*)(emaw_io + i);
    float4 ev = *(const float4*)(ema_w + i);
    float c = cs[k];
    float4 ne;
    ne.x = ev.x * 0.99f + 0.01f * dv.x;
    ne.y = ev.y * 0.99f + 0.01f * dv.y;
    ne.z = ev.z * 0.99f + 0.01f * dv.z;
    ne.w = ev.w * 0.99f + 0.01f * dv.w;
    *(float4*)(emaw_io + i) = ne;
    float4 nw = make_float4(ne.x / c, ne.y / c, ne.z / c, ne.w / c);
    *(float4*)(wout + i) = nw;
}

// ---------------- z_q gather + straight-through + loss partial -------------
__global__ void k_zq(const float* __restrict__ z,
                     const float* __restrict__ wnew,
                     const int* __restrict__ idxi,
                     float* __restrict__ zq,
                     float* __restrict__ sqacc) {   // 256 accumulators
    __shared__ float red[4];
    int i = (blockIdx.x * 256 + threadIdx.x) * 4;
    int n = i >> 8;
    int d = i & 255;
    int k = idxi[n];
    float4 wv = *(const float4*)(wnew + (k << 8) + d);
    float4 zv = *(const float4*)(z + i);
    float4 o;
    o.x = zv.x + (wv.x - zv.x);
    o.y = zv.y + (wv.y - zv.y);
    o.z = zv.z + (wv.z - zv.z);
    o.w = zv.w + (wv.w - zv.w);
    *(float4*)(zq + i) = o;
    float dx = wv.x - zv.x, dy = wv.y - zv.y, dz = wv.z - zv.z, dw_ = wv.w - zv.w;
    float s = dx*dx + dy*dy + dz*dz + dw_*dw_;
    #pragma unroll
    for (int off = 32; off; off >>= 1) s += __shfl_down(s, off);
    int lane = threadIdx.x & 63;
    if (lane == 0) red[threadIdx.x >> 6] = s;
    __syncthreads();
    if (threadIdx.x == 0)
        atomicAdd(&sqacc[blockIdx.x & 255], red[0] + red[1] + red[2] + red[3]);
}

__global__ void k_final(const float* __restrict__ sqacc, float* __restrict__ loss) {
    __shared__ float red[4];
    int t = threadIdx.x;
    float s = sqacc[t];
    #pragma unroll
    for (int off = 32; off; off >>= 1) s += __shfl_down(s, off);
    if ((t & 63) == 0) red[t >> 6] = s;
    __syncthreads();
    if (t == 0)
        loss[0] = 1.25f * (red[0] + red[1] + red[2] + red[3]) * (1.0f / 16777216.0f);
}

extern "C" void kernel_launch(void* const* d_in, const int* in_sizes, int n_in,
                              void* d_out, int out_size, void* d_ws, size_t ws_size,
                              hipStream_t stream) {
    const float* z      = (const float*)d_in[0];
    const float* weight = (const float*)d_in[1];
    const float* ema_w  = (const float*)d_in[2];
    const float* ema_cs = (const float*)d_in[3];
    float* out = (float*)d_out;
    float* ws  = (float*)d_ws;

    float* scal = ws + 4096;             // 256 floats
    int*   idxi = (int*)(ws + 8192);     // 65536 ints

    unsigned* zbf    = (unsigned*)(out + O_ZQ);
    uint4*    wsw4   = (uint4*)(out + O_ZQ + OFF_WSW);
    int*      ccnt   = (int*)(out + O_ZQ + OFF_CCNT);
    int*      cids   = (int*)(out + O_ZQ + OFF_CIDS);
    int*      offs   = (int*)(out + O_ZQ + OFF_OFFS);
    int*      cursor = (int*)(out + O_ZQ + OFF_CUR);
    int*      rows   = (int*)(out + O_ZQ + OFF_ROWS);
    unsigned* gmin   = (unsigned*)(out + O_ZQ + OFF_GMIN);
    float*    zz     = out + O_EMAW;           // dead before k_dw writes dw
    float*    wwg    = out + O_EMAW + 65536;

    hipMemsetAsync(scal,       0,    256 * 4, stream);
    hipMemsetAsync(out + O_CS, 0,    (size_t)KCB * 4, stream);
    hipMemsetAsync(ccnt,       0,    (size_t)NPTS * 4, stream);
    hipMemsetAsync(gmin,       0xFF, (size_t)NPTS * 4, stream);

    k_prepz  <<<NPTS / 4, 256, 0, stream>>>(z, zbf, zz);
    k_prepw  <<<KCB  / 4, 256, 0, stream>>>(weight, (unsigned*)wsw4, wwg);
    k_pass0  <<<512, 256, 0, stream>>>(zbf, wsw4, wwg, gmin);
    k_pass1  <<<512, 256, 0, stream>>>(zbf, wsw4, wwg, gmin, ccnt, cids);
    k_refine <<<NPTS / 4, 256, 0, stream>>>(z, weight, zz, wwg, ccnt, cids,
                                            out + O_CS, idxi, out + O_IDX);
    k_offsets<<<1, 1024, 0, stream>>>(out + O_CS, offs, cursor);
    k_fill   <<<NPTS / 256, 256, 0, stream>>>(idxi, cursor, rows);
    k_cs     <<<1, 1024, 0, stream>>>(ema_cs, out + O_CS, out + O_PERP);
    k_dw     <<<KCB, 256, 0, stream>>>(z, offs, rows, out + O_EMAW);
    k_emaw   <<<(KCB * DIMD) / 1024, 256, 0, stream>>>(ema_w, out + O_CS,
                                                       out + O_EMAW, out + O_W);
    k_zq     <<<(NPTS * DIMD) / 1024, 256, 0, stream>>>(z, out + O_W, idxi,
                                                        out + O_ZQ, scal);
    k_final  <<<1, 256, 0, stream>>>(scal, out + O_LOSS);
}

// Round 2
// 532.127 us; speedup vs baseline: 1.4750x; 1.3193x over previous
//
#include <hip/hip_runtime.h>
#include <math.h>

#define NPTS 65536
#define DIMD 256
#define KCB  4096
#define MARGIN 2.0f

// d_out float32 offsets (reference tuple order, flattened)
#define O_ZQ   0
#define O_IDX  16777216
#define O_LOSS 16842752
#define O_PERP 16842753
#define O_CS   16842754
#define O_EMAW 16846850
#define O_W    17895426

// scratch inside d_out O_ZQ region (16,777,216 floats; dead until k_zq):
#define OFF_WSW   8388608      // swizzled w bf16: 256 grp x 8 chunk x 1024 B
#define OFF_CCNT  8912896      // 65536 ints
#define OFF_CIDS  8978432      // 65536 x 16 ints
#define OFF_OFFS  10027008     // 4097 ints
#define OFF_CUR   10031232     // 4096 ints
#define OFF_ROWS  10035328     // 65536 ints
#define OFF_GMIN  10100864     // 65536 uints
#define OFF_CHOF  10166400     // 4097 ints (chunk prefix)
// zz -> EMAW region [0,65536); wwg -> EMAW [65536,69632)  (dead before k_dw)

#define CHK 64                 // rows per dw chunk
#define MAXCHUNKS 5120         // 4096 + 65536/64 upper bound

typedef __attribute__((ext_vector_type(8))) short short8;   // 8 bf16
typedef __attribute__((ext_vector_type(4))) float f32x4;

__device__ __forceinline__ unsigned short f2bf(float f) {   // RNE
    unsigned u = __float_as_uint(f);
    return (unsigned short)((u + 0x7FFF + ((u >> 16) & 1)) >> 16);
}
__device__ __forceinline__ unsigned encf(float f) {         // order-preserving
    unsigned u = __float_as_uint(f);
    return (u >> 31) ? ~u : (u | 0x80000000u);
}
__device__ __forceinline__ float decf(unsigned e) {
    unsigned u = (e & 0x80000000u) ? (e & 0x7fffffffu) : ~e;
    return __uint_as_float(u);
}

// ---------------- z: fp32 -> bf16 row-layout + row sum-of-squares ----------
__global__ void k_prepz(const float* __restrict__ src, unsigned* __restrict__ dst,
                        float* __restrict__ ss) {
    int l   = threadIdx.x & 63;
    int row = blockIdx.x * 4 + (threadIdx.x >> 6);
    float4 v = ((const float4*)(src + (size_t)row * DIMD))[l];
    uint2 pk = make_uint2(f2bf(v.x) | (f2bf(v.y) << 16),
                          f2bf(v.z) | (f2bf(v.w) << 16));
    ((uint2*)dst)[(size_t)row * 64 + l] = pk;
    float s = v.x*v.x + v.y*v.y + v.z*v.z + v.w*v.w;
    #pragma unroll
    for (int off = 32; off; off >>= 1) s += __shfl_down(s, off);
    if (l == 0) ss[row] = s;
}

// ---------------- w: fp32 -> bf16 B-frag-swizzled + sum-of-squares ---------
// dest layout: group g (=k>>4), chunk c (=d>>5): 1 KB block, lane l=q*16+n16
// holds B[k=g*16+n16][kdim=c*32+q*8+j], 16 B per lane.
__global__ void k_prepw(const float* __restrict__ src, unsigned* __restrict__ dst,
                        float* __restrict__ ss) {
    int l   = threadIdx.x & 63;
    int row = blockIdx.x * 4 + (threadIdx.x >> 6);
    float4 v = ((const float4*)(src + (size_t)row * DIMD))[l];
    uint2 pk = make_uint2(f2bf(v.x) | (f2bf(v.y) << 16),
                          f2bf(v.z) | (f2bf(v.w) << 16));
    int g = row >> 4, n16 = row & 15;
    int c = l >> 3, q = (l >> 1) & 3, half = l & 1;
    ((uint2*)dst)[g * 1024 + c * 128 + (q * 16 + n16) * 2 + half] = pk;
    float s = v.x*v.x + v.y*v.y + v.z*v.z + v.w*v.w;
    #pragma unroll
    for (int off = 32; off; off >>= 1) s += __shfl_down(s, off);
    if (l == 0) ss[row] = s;
}

// ============ staged coarse sweep (m97 pattern) ============
// Block = 4 waves x 64 rows = 256 rows, one K-half (2048 codes).
// B staged global->LDS (double-buffered, 4 groups = 32 KB per buffer) via
// global_load_lds (zero VGPR staging cost); buffer order staggered per block
// (phase) to decorrelate L2 channel traffic across the 512 blocks.
#define BUFG 4
#define NBUF 32   // 128 groups per half / BUFG

// ---------------- pass 0: per-row bf16-core min ----------------
__launch_bounds__(256, 2)
__global__ void k_pass0(const unsigned* __restrict__ zbf,
                        const uint4* __restrict__ wsw4,
                        const float* __restrict__ wwg,
                        unsigned* __restrict__ gmin) {
    __shared__ __align__(16) char smem[2][BUFG * 8192];
    const int t = threadIdx.x, wv = t >> 6, l = t & 63;
    const int q = l >> 4, n16 = l & 15;
    const int rb    = blockIdx.x >> 1;
    const int half  = blockIdx.x & 1;
    const int row0  = rb * 256 + wv * 64;
    const int g0    = half * 128;
    const int phase = (blockIdx.x * 7) & 31;

    union U { uint4 u; short8 s; } afr[4][8];
    #pragma unroll
    for (int s = 0; s < 4; ++s) {
        const char* zb = (const char*)zbf + ((size_t)(row0 + s * 16 + n16) << 9) + q * 16;
        #pragma unroll
        for (int c = 0; c < 8; ++c) afr[s][c].u = *(const uint4*)(zb + c * 64);
    }

    // stage buffer-slot 'which' with staggered buffer index bi (0..NBUF-1)
    auto stage = [&](int which, int bi) {
        const uint4* srcb = wsw4 + (size_t)(g0 + ((phase + bi) & 31) * BUFG) * 512;
        #pragma unroll
        for (int j = 0; j < 8; ++j) {
            int rrow = j * 4 + wv;                      // 1 KB row of the 32 KB tile
            __builtin_amdgcn_global_load_lds(
                (const __attribute__((address_space(1))) unsigned*)(srcb + rrow * 64 + l),
                (__attribute__((address_space(3))) unsigned*)(&smem[which][rrow * 1024]),
                16, 0, 0);
        }
    };

    float minv[16];
    #pragma unroll
    for (int i = 0; i < 16; ++i) minv[i] = 3.0e38f;

    stage(0, 0);
    __syncthreads();                                    // drains vmcnt(0) implicitly

    for (int b = 0; b < NBUF; ++b) {
        const int cur = b & 1;
        if (b + 1 < NBUF) stage(cur ^ 1, b + 1);        // async prefetch next tile
        const char* sbase = smem[cur];
        const int ggb = g0 + ((phase + b) & 31) * BUFG;
        #pragma unroll
        for (int g2 = 0; g2 < BUFG; ++g2) {
            f32x4 acc[4];
            #pragma unroll
            for (int s = 0; s < 4; ++s) acc[s] = (f32x4){0.f, 0.f, 0.f, 0.f};
            #pragma unroll
            for (int c = 0; c < 8; ++c) {
                U bf; bf.u = *(const uint4*)(sbase + g2 * 8192 + c * 1024 + (l << 4));
                #pragma unroll
                for (int s = 0; s < 4; ++s)
                    acc[s] = __builtin_amdgcn_mfma_f32_16x16x32_bf16(afr[s][c].s, bf.s, acc[s], 0, 0, 0);
            }
            float wwv = wwg[(ggb + g2) * 16 + n16];
            #pragma unroll
            for (int s = 0; s < 4; ++s)
                #pragma unroll
                for (int r = 0; r < 4; ++r)
                    minv[s*4+r] = fminf(minv[s*4+r], fmaf(-2.f, acc[s][r], wwv));
        }
        __syncthreads();                                // vmcnt drain + reuse fence
    }

    #pragma unroll
    for (int i = 0; i < 16; ++i) {
        float m = minv[i];
        #pragma unroll
        for (int msk = 1; msk < 16; msk <<= 1) m = fminf(m, __shfl_xor(m, msk));
        if (n16 == 0)
            atomicMin(&gmin[row0 + (i >> 2) * 16 + q * 4 + (i & 3)], encf(m));
    }
}

// ---------------- pass 1: emit margin candidates ----------------
__launch_bounds__(256, 2)
__global__ void k_pass1(const unsigned* __restrict__ zbf,
                        const uint4* __restrict__ wsw4,
                        const float* __restrict__ wwg,
                        const unsigned* __restrict__ gmin,
                        int* __restrict__ ccnt,
                        int* __restrict__ cids) {
    __shared__ __align__(16) char smem[2][BUFG * 8192];
    const int t = threadIdx.x, wv = t >> 6, l = t & 63;
    const int q = l >> 4, n16 = l & 15;
    const int rb    = blockIdx.x >> 1;
    const int half  = blockIdx.x & 1;
    const int row0  = rb * 256 + wv * 64;
    const int g0    = half * 128;
    const int phase = (blockIdx.x * 7) & 31;

    union U { uint4 u; short8 s; } afr[4][8];
    #pragma unroll
    for (int s = 0; s < 4; ++s) {
        const char* zb = (const char*)zbf + ((size_t)(row0 + s * 16 + n16) << 9) + q * 16;
        #pragma unroll
        for (int c = 0; c < 8; ++c) afr[s][c].u = *(const uint4*)(zb + c * 64);
    }

    auto stage = [&](int which, int bi) {
        const uint4* srcb = wsw4 + (size_t)(g0 + ((phase + bi) & 31) * BUFG) * 512;
        #pragma unroll
        for (int j = 0; j < 8; ++j) {
            int rrow = j * 4 + wv;
            __builtin_amdgcn_global_load_lds(
                (const __attribute__((address_space(1))) unsigned*)(srcb + rrow * 64 + l),
                (__attribute__((address_space(3))) unsigned*)(&smem[which][rrow * 1024]),
                16, 0, 0);
        }
    };

    float thr[16];
    #pragma unroll
    for (int i = 0; i < 16; ++i)
        thr[i] = decf(gmin[row0 + (i >> 2) * 16 + q * 4 + (i & 3)]) + MARGIN;

    stage(0, 0);
    __syncthreads();

    for (int b = 0; b < NBUF; ++b) {
        const int cur = b & 1;
        if (b + 1 < NBUF) stage(cur ^ 1, b + 1);
        const char* sbase = smem[cur];
        const int ggb = g0 + ((phase + b) & 31) * BUFG;
        #pragma unroll
        for (int g2 = 0; g2 < BUFG; ++g2) {
            f32x4 acc[4];
            #pragma unroll
            for (int s = 0; s < 4; ++s) acc[s] = (f32x4){0.f, 0.f, 0.f, 0.f};
            #pragma unroll
            for (int c = 0; c < 8; ++c) {
                U bf; bf.u = *(const uint4*)(sbase + g2 * 8192 + c * 1024 + (l << 4));
                #pragma unroll
                for (int s = 0; s < 4; ++s)
                    acc[s] = __builtin_amdgcn_mfma_f32_16x16x32_bf16(afr[s][c].s, bf.s, acc[s], 0, 0, 0);
            }
            const int gg = ggb + g2;
            float wwv = wwg[gg * 16 + n16];
            #pragma unroll
            for (int s = 0; s < 4; ++s)
                #pragma unroll
                for (int r = 0; r < 4; ++r) {
                    float core = fmaf(-2.f, acc[s][r], wwv);
                    if (core <= thr[s*4+r]) {
                        int row = row0 + s * 16 + q * 4 + r;
                        int pos = atomicAdd(&ccnt[row], 1);
                        if (pos < 16) cids[row * 16 + pos] = gg * 16 + n16;
                    }
                }
        }
        __syncthreads();
    }
}

// ---------------- fp32 rescore of candidates ----------------
__global__ void k_refine(const float* __restrict__ z,
                         const float* __restrict__ w,
                         const float* __restrict__ zz,
                         const float* __restrict__ wwg,
                         const int* __restrict__ ccnt,
                         const int* __restrict__ cids,
                         float* __restrict__ counts,
                         int*   __restrict__ idxi,
                         float* __restrict__ idxf) {
    int l   = threadIdx.x & 63;
    int row = blockIdx.x * 4 + (threadIdx.x >> 6);
    int n = ccnt[row]; if (n > 16) n = 16;
    float4 zv = ((const float4*)(z + (size_t)row * DIMD))[l];
    float zzv = zz[row];
    float bd = 3.0e38f; int bi = 0x7fffffff;
    for (int j = 0; j < n; ++j) {
        int k = cids[row * 16 + j];
        float4 wv = ((const float4*)(w + (size_t)k * DIMD))[l];
        float s = zv.x*wv.x + zv.y*wv.y + zv.z*wv.z + zv.w*wv.w;
        #pragma unroll
        for (int off = 32; off; off >>= 1) s += __shfl_xor(s, off);
        float d = (zzv + wwg[k]) - 2.0f * s;
        if (d < bd || (d == bd && k < bi)) { bd = d; bi = k; }
    }
    if (l == 0) {
        idxi[row] = bi;
        idxf[row] = (float)bi;
        atomicAdd(&counts[bi], 1.0f);
    }
}

// ------- exclusive prefix sums: counts -> offs/cursor, ceil(c/CHK) -> choffs
__global__ void k_offsets(const float* __restrict__ counts,
                          int* __restrict__ offs, int* __restrict__ cursor,
                          int* __restrict__ choffs) {
    __shared__ int sc[1024];
    int t = threadIdx.x;
    int c[4]; int s = 0;
    #pragma unroll
    for (int i = 0; i < 4; ++i) { c[i] = (int)counts[t * 4 + i]; s += c[i]; }
    sc[t] = s;
    __syncthreads();
    for (int d = 1; d < 1024; d <<= 1) {
        int v = (t >= d) ? sc[t - d] : 0;
        __syncthreads();
        sc[t] += v;
        __syncthreads();
    }
    int o = sc[t] - s;
    #pragma unroll
    for (int i = 0; i < 4; ++i) { offs[t*4+i] = o; cursor[t*4+i] = o; o += c[i]; }
    if (t == 1023) offs[4096] = sc[1023];
    __syncthreads();

    // second scan: chunk counts
    int ch[4]; int s2 = 0;
    #pragma unroll
    for (int i = 0; i < 4; ++i) { ch[i] = (c[i] + CHK - 1) / CHK; s2 += ch[i]; }
    sc[t] = s2;
    __syncthreads();
    for (int d = 1; d < 1024; d <<= 1) {
        int v = (t >= d) ? sc[t - d] : 0;
        __syncthreads();
        sc[t] += v;
        __syncthreads();
    }
    int o2 = sc[t] - s2;
    #pragma unroll
    for (int i = 0; i < 4; ++i) { choffs[t*4+i] = o2; o2 += ch[i]; }
    if (t == 1023) choffs[4096] = sc[1023];
}

// ---------------- fill inverted row lists ----------------
__global__ void k_fill(const int* __restrict__ idxi, int* __restrict__ cursor,
                       int* __restrict__ rows) {
    int r = blockIdx.x * 256 + threadIdx.x;
    int k = idxi[r];
    int pos = atomicAdd(&cursor[k], 1);
    rows[pos] = r;
}

// ---------------- dw[k,:] += sum of z rows in chunk (chunk-parallel) ------
// One block per 64-row chunk of the sorted rows[] array; binary search maps
// block -> (cluster, chunk). 4 row-slots x 64 d-lanes. Multi-chunk clusters
// flush via atomicAdd into the pre-zeroed dw; single-chunk clusters store.
__global__ void k_dw(const float* __restrict__ z, const int* __restrict__ offs,
                     const int* __restrict__ choffs, const int* __restrict__ rows,
                     float* __restrict__ dw) {
    __shared__ float4 part[4][64];
    int b = blockIdx.x;
    if (b >= choffs[KCB]) return;
    int lo = 0, hi = KCB;               // invariant: choffs[lo] <= b < choffs[hi]
    while (hi - lo > 1) { int mid = (lo + hi) >> 1; if (choffs[mid] <= b) lo = mid; else hi = mid; }
    int k  = lo;
    int ci = b - choffs[k];
    int o0 = offs[k] + ci * CHK;
    int o1 = offs[k + 1]; if (o1 > o0 + CHK) o1 = o0 + CHK;
    int l = threadIdx.x & 63, j = threadIdx.x >> 6;
    float4 a = make_float4(0.f, 0.f, 0.f, 0.f);
    for (int i = o0 + j; i < o1; i += 4) {
        int r = rows[i];
        float4 v = ((const float4*)(z + (size_t)r * DIMD))[l];
        a.x += v.x; a.y += v.y; a.z += v.z; a.w += v.w;
    }
    part[j][l] = a;
    __syncthreads();
    if (j == 0) {
        float4 bb = part[0][l], c = part[1][l], d = part[2][l], e = part[3][l];
        a = make_float4(bb.x+c.x+d.x+e.x, bb.y+c.y+d.y+e.y,
                        bb.z+c.z+d.z+e.z, bb.w+c.w+d.w+e.w);
        float* p = dw + (size_t)k * DIMD + l * 4;
        if (choffs[k + 1] - choffs[k] == 1) {
            *(float4*)p = a;
        } else {
            atomicAdd(p + 0, a.x); atomicAdd(p + 1, a.y);
            atomicAdd(p + 2, a.z); atomicAdd(p + 3, a.w);
        }
    }
}

// ---------------- cluster-size EMA + perplexity ----------------
__global__ void k_cs(const float* __restrict__ ema_cs,
                     float* __restrict__ cs_io,
                     float* __restrict__ perp) {
    __shared__ float2 red[16];
    int t = threadIdx.x;
    float csd[4];
    float nl = 0.f, el = 0.f;
    #pragma unroll
    for (int i = 0; i < 4; ++i) {
        int k = t * 4 + i;
        float c  = cs_io[k];
        float cd = ema_cs[k] * 0.99f + 0.01f * c;
        csd[i] = cd;
        nl += cd;
        float p = c * (1.0f / 65536.0f);
        el += p * logf(p + 1e-10f);
    }
    #pragma unroll
    for (int off = 32; off; off >>= 1) { nl += __shfl_down(nl, off); el += __shfl_down(el, off); }
    if ((t & 63) == 0) red[t >> 6] = make_float2(nl, el);
    __syncthreads();
    if (t == 0) {
        float n = 0.f, e = 0.f;
        for (int i = 0; i < 16; ++i) { n += red[i].x; e += red[i].y; }
        red[0] = make_float2(n, e);
        perp[0] = expf(-e);
    }
    __syncthreads();
    float n = red[0].x;
    float scale = n / (n + 4096.0f * 1e-5f);
    #pragma unroll
    for (int i = 0; i < 4; ++i)
        cs_io[t * 4 + i] = (csd[i] + 1e-5f) * scale;
}

// ---------------- new_ema_w (in-place over dw) + new_weight ----------------
__global__ void k_emaw(const float* __restrict__ ema_w,
                       const float* __restrict__ cs,
                       float* __restrict__ emaw_io,
                       float* __restrict__ wout) {
    int i = (blockIdx.x * 256 + threadIdx.x) * 4;
    int k = i >> 8;
    float4 dv = *(const float4*)(emaw_io + i);
    float4 ev = *(const float4*)(ema_w + i);
    float c = cs[k];
    float4 ne;
    ne.x = ev.x * 0.99f + 0.01f * dv.x;
    ne.y = ev.y * 0.99f + 0.01f * dv.y;
    ne.z = ev.z * 0.99f + 0.01f * dv.z;
    ne.w = ev.w * 0.99f + 0.01f * dv.w;
    *(float4*)(emaw_io + i) = ne;
    float4 nw = make_float4(ne.x / c, ne.y / c, ne.z / c, ne.w / c);
    *(float4*)(wout + i) = nw;
}

// ---------------- z_q gather + straight-through + loss partial -------------
__global__ void k_zq(const float* __restrict__ z,
                     const float* __restrict__ wnew,
                     const int* __restrict__ idxi,
                     float* __restrict__ zq,
                     float* __restrict__ sqacc) {   // 256 accumulators
    __shared__ float red[4];
    int i = (blockIdx.x * 256 + threadIdx.x) * 4;
    int n = i >> 8;
    int d = i & 255;
    int k = idxi[n];
    float4 wv = *(const float4*)(wnew + (k << 8) + d);
    float4 zv = *(const float4*)(z + i);
    float4 o;
    o.x = zv.x + (wv.x - zv.x);
    o.y = zv.y + (wv.y - zv.y);
    o.z = zv.z + (wv.z - zv.z);
    o.w = zv.w + (wv.w - zv.w);
    *(float4*)(zq + i) = o;
    float dx = wv.x - zv.x, dy = wv.y - zv.y, dz = wv.z - zv.z, dw_ = wv.w - zv.w;
    float s = dx*dx + dy*dy + dz*dz + dw_*dw_;
    #pragma unroll
    for (int off = 32; off; off >>= 1) s += __shfl_down(s, off);
    int lane = threadIdx.x & 63;
    if (lane == 0) red[threadIdx.x >> 6] = s;
    __syncthreads();
    if (threadIdx.x == 0)
        atomicAdd(&sqacc[blockIdx.x & 255], red[0] + red[1] + red[2] + red[3]);
}

__global__ void k_final(const float* __restrict__ sqacc, float* __restrict__ loss) {
    __shared__ float red[4];
    int t = threadIdx.x;
    float s = sqacc[t];
    #pragma unroll
    for (int off = 32; off; off >>= 1) s += __shfl_down(s, off);
    if ((t & 63) == 0) red[t >> 6] = s;
    __syncthreads();
    if (t == 0)
        loss[0] = 1.25f * (red[0] + red[1] + red[2] + red[3]) * (1.0f / 16777216.0f);
}

extern "C" void kernel_launch(void* const* d_in, const int* in_sizes, int n_in,
                              void* d_out, int out_size, void* d_ws, size_t ws_size,
                              hipStream_t stream) {
    const float* z      = (const float*)d_in[0];
    const float* weight = (const float*)d_in[1];
    const float* ema_w  = (const float*)d_in[2];
    const float* ema_cs = (const float*)d_in[3];
    float* out = (float*)d_out;
    float* ws  = (float*)d_ws;

    float* scal = ws + 4096;             // 256 floats
    int*   idxi = (int*)(ws + 8192);     // 65536 ints

    unsigned* zbf    = (unsigned*)(out + O_ZQ);
    uint4*    wsw4   = (uint4*)(out + O_ZQ + OFF_WSW);
    int*      ccnt   = (int*)(out + O_ZQ + OFF_CCNT);
    int*      cids   = (int*)(out + O_ZQ + OFF_CIDS);
    int*      offs   = (int*)(out + O_ZQ + OFF_OFFS);
    int*      cursor = (int*)(out + O_ZQ + OFF_CUR);
    int*      rows   = (int*)(out + O_ZQ + OFF_ROWS);
    unsigned* gmin   = (unsigned*)(out + O_ZQ + OFF_GMIN);
    int*      choffs = (int*)(out + O_ZQ + OFF_CHOF);
    float*    zz     = out + O_EMAW;           // dead before the dw memset
    float*    wwg    = out + O_EMAW + 65536;

    hipMemsetAsync(scal,       0,    256 * 4, stream);
    hipMemsetAsync(out + O_CS, 0,    (size_t)KCB * 4, stream);
    hipMemsetAsync(ccnt,       0,    (size_t)NPTS * 4, stream);
    hipMemsetAsync(gmin,       0xFF, (size_t)NPTS * 4, stream);

    k_prepz  <<<NPTS / 4, 256, 0, stream>>>(z, zbf, zz);
    k_prepw  <<<KCB  / 4, 256, 0, stream>>>(weight, (unsigned*)wsw4, wwg);
    k_pass0  <<<512, 256, 0, stream>>>(zbf, wsw4, wwg, gmin);
    k_pass1  <<<512, 256, 0, stream>>>(zbf, wsw4, wwg, gmin, ccnt, cids);
    k_refine <<<NPTS / 4, 256, 0, stream>>>(z, weight, zz, wwg, ccnt, cids,
                                            out + O_CS, idxi, out + O_IDX);
    // zz/wwg are dead from here; zero the dw region (covers empty clusters
    // and makes the chunk-parallel atomicAdd flush correct).
    hipMemsetAsync(out + O_EMAW, 0, (size_t)KCB * DIMD * 4, stream);
    k_offsets<<<1, 1024, 0, stream>>>(out + O_CS, offs, cursor, choffs);
    k_fill   <<<NPTS / 256, 256, 0, stream>>>(idxi, cursor, rows);
    k_cs     <<<1, 1024, 0, stream>>>(ema_cs, out + O_CS, out + O_PERP);
    k_dw     <<<MAXCHUNKS, 256, 0, stream>>>(z, offs, choffs, rows, out + O_EMAW);
    k_emaw   <<<(KCB * DIMD) / 1024, 256, 0, stream>>>(ema_w, out + O_CS,
                                                       out + O_EMAW, out + O_W);
    k_zq     <<<(NPTS * DIMD) / 1024, 256, 0, stream>>>(z, out + O_W, idxi,
                                                        out + O_ZQ, scal);
    k_final  <<<1, 256, 0, stream>>>(scal, out + O_LOSS);
}

// Round 3
// 513.242 us; speedup vs baseline: 1.5293x; 1.0368x over previous
//
#include <hip/hip_runtime.h>
#include <math.h>

#define NPTS 65536
#define DIMD 256
#define KCB  4096
#define MARGIN 2.0f

// d_out float32 offsets (reference tuple order, flattened)
#define O_ZQ   0
#define O_IDX  16777216
#define O_LOSS 16842752
#define O_PERP 16842753
#define O_CS   16842754
#define O_EMAW 16846850
#define O_W    17895426

// scratch inside d_out O_ZQ region (16,777,216 floats; dead until k_zq):
#define OFF_WSW   8388608      // swizzled w bf16: 256 grp x 8 chunk x 1024 B
#define OFF_CCNT  8912896      // 65536 ints
#define OFF_CIDS  8978432      // 65536 x 16 ints
#define OFF_OFFS  10027008     // 4097 ints
#define OFF_CUR   10031232     // 4096 ints
#define OFF_ROWS  10035328     // 65536 ints
#define OFF_GMIN  10100864     // 65536 uints
#define OFF_CHOF  10166400     // 4097 ints (chunk prefix)
// zz -> EMAW region [0,65536); wwg -> EMAW [65536,69632)  (dead before k_dw)

#define CHK 64                 // rows per dw chunk
#define MAXCHUNKS 5120         // 4096 + 65536/64 upper bound

// sweep ring pipeline: 6 LDS slots x 1 group (8 KB), prefetch depth 4.
// Per phase each wave issues 2 global_load_lds; steady-state in-flight = 10,
// counted wait = vmcnt(8). Loads stay in flight across the s_barrier (T4).
#define RING 6
#define PFD  4

typedef __attribute__((ext_vector_type(8))) short short8;   // 8 bf16
typedef __attribute__((ext_vector_type(4))) float f32x4;

__device__ __forceinline__ unsigned short f2bf(float f) {   // RNE
    unsigned u = __float_as_uint(f);
    return (unsigned short)((u + 0x7FFF + ((u >> 16) & 1)) >> 16);
}
__device__ __forceinline__ unsigned encf(float f) {         // order-preserving
    unsigned u = __float_as_uint(f);
    return (u >> 31) ? ~u : (u | 0x80000000u);
}
__device__ __forceinline__ float decf(unsigned e) {
    unsigned u = (e & 0x80000000u) ? (e & 0x7fffffffu) : ~e;
    return __uint_as_float(u);
}

// ---------------- z: fp32 -> bf16 row-layout + row sum-of-squares ----------
__global__ void k_prepz(const float* __restrict__ src, unsigned* __restrict__ dst,
                        float* __restrict__ ss) {
    int l   = threadIdx.x & 63;
    int row = blockIdx.x * 4 + (threadIdx.x >> 6);
    float4 v = ((const float4*)(src + (size_t)row * DIMD))[l];
    uint2 pk = make_uint2(f2bf(v.x) | (f2bf(v.y) << 16),
                          f2bf(v.z) | (f2bf(v.w) << 16));
    ((uint2*)dst)[(size_t)row * 64 + l] = pk;
    float s = v.x*v.x + v.y*v.y + v.z*v.z + v.w*v.w;
    #pragma unroll
    for (int off = 32; off; off >>= 1) s += __shfl_down(s, off);
    if (l == 0) ss[row] = s;
}

// ---------------- w: fp32 -> bf16 B-frag-swizzled + sum-of-squares ---------
__global__ void k_prepw(const float* __restrict__ src, unsigned* __restrict__ dst,
                        float* __restrict__ ss) {
    int l   = threadIdx.x & 63;
    int row = blockIdx.x * 4 + (threadIdx.x >> 6);
    float4 v = ((const float4*)(src + (size_t)row * DIMD))[l];
    uint2 pk = make_uint2(f2bf(v.x) | (f2bf(v.y) << 16),
                          f2bf(v.z) | (f2bf(v.w) << 16));
    int g = row >> 4, n16 = row & 15;
    int c = l >> 3, q = (l >> 1) & 3, half = l & 1;
    ((uint2*)dst)[g * 1024 + c * 128 + (q * 16 + n16) * 2 + half] = pk;
    float s = v.x*v.x + v.y*v.y + v.z*v.z + v.w*v.w;
    #pragma unroll
    for (int off = 32; off; off >>= 1) s += __shfl_down(s, off);
    if (l == 0) ss[row] = s;
}

// ---------------- pass 0: per-row bf16-core min (ring pipeline) ------------
__launch_bounds__(256, 2)
__global__ void k_pass0(const unsigned* __restrict__ zbf,
                        const uint4* __restrict__ wsw4,
                        const float* __restrict__ wwg,
                        unsigned* __restrict__ gmin) {
    __shared__ __align__(16) char smem[RING * 8192];
    __shared__ float lds_ww[2048];
    const int t = threadIdx.x, wv = t >> 6, l = t & 63;
    const int q = l >> 4, n16 = l & 15;
    const int rb    = blockIdx.x >> 1;
    const int half  = blockIdx.x & 1;
    const int row0  = rb * 256 + wv * 64;
    const int g0    = half * 128;
    const int ph0   = (blockIdx.x * 37) & 127;   // scan-order stagger

    union U { uint4 u; short8 s; } afr[4][8];
    #pragma unroll
    for (int s = 0; s < 4; ++s) {
        const char* zb = (const char*)zbf + ((size_t)(row0 + s * 16 + n16) << 9) + q * 16;
        #pragma unroll
        for (int c = 0; c < 8; ++c) afr[s][c].u = *(const uint4*)(zb + c * 64);
    }

    // stage one 8 KB group into ring slot 'buf' (2 global_load_lds / wave)
    auto stage = [&](int buf, int g) {
        const int ga = (ph0 + g) & 127;
        const uint4* srcb = wsw4 + (size_t)(g0 + ga) * 512;
        #pragma unroll
        for (int j = 0; j < 2; ++j) {
            int rrow = j * 4 + wv;
            __builtin_amdgcn_global_load_lds(
                (const __attribute__((address_space(1))) unsigned*)(srcb + rrow * 64 + l),
                (__attribute__((address_space(3))) unsigned*)(&smem[buf * 8192 + rrow * 1024]),
                16, 0, 0);
        }
    };

    // prologue: ww -> LDS, prefetch groups 0..PFD-1, one full drain
    for (int i = t; i < 2048; i += 256) lds_ww[i] = wwg[g0 * 16 + i];
    #pragma unroll
    for (int g = 0; g < PFD; ++g) stage(g, g);
    __syncthreads();

    float minv[16];
    #pragma unroll
    for (int i = 0; i < 16; ++i) minv[i] = 3.0e38f;

    int buf = 0, sbuf = PFD;
    #pragma unroll 1
    for (int g = 0; g < 128 - PFD; ++g) {
        stage(sbuf, g + PFD);
        sbuf = (sbuf == RING - 1) ? 0 : sbuf + 1;
        asm volatile("s_waitcnt vmcnt(8)" ::: "memory");
        __builtin_amdgcn_s_barrier();
        const char* sbase = smem + buf * 8192;
        buf = (buf == RING - 1) ? 0 : buf + 1;
        const int ga = (ph0 + g) & 127;
        f32x4 acc[4];
        #pragma unroll
        for (int s = 0; s < 4; ++s) acc[s] = (f32x4){0.f, 0.f, 0.f, 0.f};
        __builtin_amdgcn_s_setprio(1);
        #pragma unroll
        for (int c = 0; c < 8; ++c) {
            U bf; bf.u = *(const uint4*)(sbase + c * 1024 + (l << 4));
            #pragma unroll
            for (int s = 0; s < 4; ++s)
                acc[s] = __builtin_amdgcn_mfma_f32_16x16x32_bf16(afr[s][c].s, bf.s, acc[s], 0, 0, 0);
        }
        __builtin_amdgcn_s_setprio(0);
        float wwv = lds_ww[ga * 16 + n16];
        #pragma unroll
        for (int s = 0; s < 4; ++s)
            #pragma unroll
            for (int r = 0; r < 4; ++r)
                minv[s*4+r] = fminf(minv[s*4+r], fmaf(-2.f, acc[s][r], wwv));
    }
    #pragma unroll 1
    for (int g = 128 - PFD; g < 128; ++g) {
        asm volatile("s_waitcnt vmcnt(0)" ::: "memory");
        __builtin_amdgcn_s_barrier();
        const char* sbase = smem + buf * 8192;
        buf = (buf == RING - 1) ? 0 : buf + 1;
        const int ga = (ph0 + g) & 127;
        f32x4 acc[4];
        #pragma unroll
        for (int s = 0; s < 4; ++s) acc[s] = (f32x4){0.f, 0.f, 0.f, 0.f};
        #pragma unroll
        for (int c = 0; c < 8; ++c) {
            U bf; bf.u = *(const uint4*)(sbase + c * 1024 + (l << 4));
            #pragma unroll
            for (int s = 0; s < 4; ++s)
                acc[s] = __builtin_amdgcn_mfma_f32_16x16x32_bf16(afr[s][c].s, bf.s, acc[s], 0, 0, 0);
        }
        float wwv = lds_ww[ga * 16 + n16];
        #pragma unroll
        for (int s = 0; s < 4; ++s)
            #pragma unroll
            for (int r = 0; r < 4; ++r)
                minv[s*4+r] = fminf(minv[s*4+r], fmaf(-2.f, acc[s][r], wwv));
    }

    #pragma unroll
    for (int i = 0; i < 16; ++i) {
        float m = minv[i];
        #pragma unroll
        for (int msk = 1; msk < 16; msk <<= 1) m = fminf(m, __shfl_xor(m, msk));
        if (n16 == 0)
            atomicMin(&gmin[row0 + (i >> 2) * 16 + q * 4 + (i & 3)], encf(m));
    }
}

// ---------------- pass 1: emit margin candidates (ring pipeline) -----------
// Emissions go to per-row LDS lists (DS-domain atomics keep the counted
// vmcnt exact); flushed to global ccnt/cids once at the end.
__launch_bounds__(256, 2)
__global__ void k_pass1(const unsigned* __restrict__ zbf,
                        const uint4* __restrict__ wsw4,
                        const float* __restrict__ wwg,
                        const unsigned* __restrict__ gmin,
                        int* __restrict__ ccnt,
                        int* __restrict__ cids) {
    __shared__ __align__(16) char smem[RING * 8192];
    __shared__ float lds_ww[2048];
    __shared__ int   lds_cnt[256];
    __shared__ short lds_cid[256 * 16];
    const int t = threadIdx.x, wv = t >> 6, l = t & 63;
    const int q = l >> 4, n16 = l & 15;
    const int rb    = blockIdx.x >> 1;
    const int half  = blockIdx.x & 1;
    const int row0  = rb * 256 + wv * 64;
    const int g0    = half * 128;
    const int ph0   = (blockIdx.x * 37) & 127;

    union U { uint4 u; short8 s; } afr[4][8];
    #pragma unroll
    for (int s = 0; s < 4; ++s) {
        const char* zb = (const char*)zbf + ((size_t)(row0 + s * 16 + n16) << 9) + q * 16;
        #pragma unroll
        for (int c = 0; c < 8; ++c) afr[s][c].u = *(const uint4*)(zb + c * 64);
    }

    auto stage = [&](int buf, int g) {
        const int ga = (ph0 + g) & 127;
        const uint4* srcb = wsw4 + (size_t)(g0 + ga) * 512;
        #pragma unroll
        for (int j = 0; j < 2; ++j) {
            int rrow = j * 4 + wv;
            __builtin_amdgcn_global_load_lds(
                (const __attribute__((address_space(1))) unsigned*)(srcb + rrow * 64 + l),
                (__attribute__((address_space(3))) unsigned*)(&smem[buf * 8192 + rrow * 1024]),
                16, 0, 0);
        }
    };

    float thr[16];
    #pragma unroll
    for (int i = 0; i < 16; ++i)
        thr[i] = decf(gmin[row0 + (i >> 2) * 16 + q * 4 + (i & 3)]) + MARGIN;

    for (int i = t; i < 2048; i += 256) lds_ww[i] = wwg[g0 * 16 + i];
    lds_cnt[t] = 0;
    #pragma unroll
    for (int g = 0; g < PFD; ++g) stage(g, g);
    __syncthreads();

    int buf = 0, sbuf = PFD;
    #pragma unroll 1
    for (int g = 0; g < 128; ++g) {
        if (g < 128 - PFD) {
            stage(sbuf, g + PFD);
            sbuf = (sbuf == RING - 1) ? 0 : sbuf + 1;
            asm volatile("s_waitcnt vmcnt(8)" ::: "memory");
        } else {
            asm volatile("s_waitcnt vmcnt(0)" ::: "memory");
        }
        __builtin_amdgcn_s_barrier();
        const char* sbase = smem + buf * 8192;
        buf = (buf == RING - 1) ? 0 : buf + 1;
        const int ga = (ph0 + g) & 127;
        f32x4 acc[4];
        #pragma unroll
        for (int s = 0; s < 4; ++s) acc[s] = (f32x4){0.f, 0.f, 0.f, 0.f};
        __builtin_amdgcn_s_setprio(1);
        #pragma unroll
        for (int c = 0; c < 8; ++c) {
            U bf; bf.u = *(const uint4*)(sbase + c * 1024 + (l << 4));
            #pragma unroll
            for (int s = 0; s < 4; ++s)
                acc[s] = __builtin_amdgcn_mfma_f32_16x16x32_bf16(afr[s][c].s, bf.s, acc[s], 0, 0, 0);
        }
        __builtin_amdgcn_s_setprio(0);
        const int gg = g0 + ga;
        float wwv = lds_ww[ga * 16 + n16];
        #pragma unroll
        for (int s = 0; s < 4; ++s)
            #pragma unroll
            for (int r = 0; r < 4; ++r) {
                float core = fmaf(-2.f, acc[s][r], wwv);
                if (core <= thr[s*4+r]) {
                    int rl = wv * 64 + s * 16 + q * 4 + r;
                    int p = atomicAdd(&lds_cnt[rl], 1);
                    if (p < 16) lds_cid[rl * 16 + p] = (short)(gg * 16 + n16);
                }
            }
    }

    __syncthreads();
    int n = lds_cnt[t];
    if (n > 0) {
        int rg = rb * 256 + t;
        int base = atomicAdd(&ccnt[rg], n);
        int m = n > 16 ? 16 : n;
        for (int j = 0; j < m; ++j) {
            int p = base + j;
            if (p < 16) cids[rg * 16 + p] = (int)lds_cid[t * 16 + j];
        }
    }
}

// ---------------- fp32 rescore of candidates ----------------
__global__ void k_refine(const float* __restrict__ z,
                         const float* __restrict__ w,
                         const float* __restrict__ zz,
                         const float* __restrict__ wwg,
                         const int* __restrict__ ccnt,
                         const int* __restrict__ cids,
                         float* __restrict__ counts,
                         int*   __restrict__ idxi,
                         float* __restrict__ idxf) {
    int l   = threadIdx.x & 63;
    int row = blockIdx.x * 4 + (threadIdx.x >> 6);
    int n = ccnt[row]; if (n > 16) n = 16;
    float4 zv = ((const float4*)(z + (size_t)row * DIMD))[l];
    float zzv = zz[row];
    float bd = 3.0e38f; int bi = 0x7fffffff;
    for (int j = 0; j < n; ++j) {
        int k = cids[row * 16 + j];
        float4 wv = ((const float4*)(w + (size_t)k * DIMD))[l];
        float s = zv.x*wv.x + zv.y*wv.y + zv.z*wv.z + zv.w*wv.w;
        #pragma unroll
        for (int off = 32; off; off >>= 1) s += __shfl_xor(s, off);
        float d = (zzv + wwg[k]) - 2.0f * s;
        if (d < bd || (d == bd && k < bi)) { bd = d; bi = k; }
    }
    if (l == 0) {
        idxi[row] = bi;
        idxf[row] = (float)bi;
        atomicAdd(&counts[bi], 1.0f);
    }
}

// ------- exclusive prefix sums: counts -> offs/cursor, ceil(c/CHK) -> choffs
__global__ void k_offsets(const float* __restrict__ counts,
                          int* __restrict__ offs, int* __restrict__ cursor,
                          int* __restrict__ choffs) {
    __shared__ int sc[1024];
    int t = threadIdx.x;
    int c[4]; int s = 0;
    #pragma unroll
    for (int i = 0; i < 4; ++i) { c[i] = (int)counts[t * 4 + i]; s += c[i]; }
    sc[t] = s;
    __syncthreads();
    for (int d = 1; d < 1024; d <<= 1) {
        int v = (t >= d) ? sc[t - d] : 0;
        __syncthreads();
        sc[t] += v;
        __syncthreads();
    }
    int o = sc[t] - s;
    #pragma unroll
    for (int i = 0; i < 4; ++i) { offs[t*4+i] = o; cursor[t*4+i] = o; o += c[i]; }
    if (t == 1023) offs[4096] = sc[1023];
    __syncthreads();

    int ch[4]; int s2 = 0;
    #pragma unroll
    for (int i = 0; i < 4; ++i) { ch[i] = (c[i] + CHK - 1) / CHK; s2 += ch[i]; }
    sc[t] = s2;
    __syncthreads();
    for (int d = 1; d < 1024; d <<= 1) {
        int v = (t >= d) ? sc[t - d] : 0;
        __syncthreads();
        sc[t] += v;
        __syncthreads();
    }
    int o2 = sc[t] - s2;
    #pragma unroll
    for (int i = 0; i < 4; ++i) { choffs[t*4+i] = o2; o2 += ch[i]; }
    if (t == 1023) choffs[4096] = sc[1023];
}

// ---------------- fill inverted row lists ----------------
__global__ void k_fill(const int* __restrict__ idxi, int* __restrict__ cursor,
                       int* __restrict__ rows) {
    int r = blockIdx.x * 256 + threadIdx.x;
    int k = idxi[r];
    int pos = atomicAdd(&cursor[k], 1);
    rows[pos] = r;
}

// ---------------- dw[k,:] += sum of z rows in chunk (chunk-parallel) ------
__global__ void k_dw(const float* __restrict__ z, const int* __restrict__ offs,
                     const int* __restrict__ choffs, const int* __restrict__ rows,
                     float* __restrict__ dw) {
    __shared__ float4 part[4][64];
    int b = blockIdx.x;
    if (b >= choffs[KCB]) return;
    int lo = 0, hi = KCB;
    while (hi - lo > 1) { int mid = (lo + hi) >> 1; if (choffs[mid] <= b) lo = mid; else hi = mid; }
    int k  = lo;
    int ci = b - choffs[k];
    int o0 = offs[k] + ci * CHK;
    int o1 = offs[k + 1]; if (o1 > o0 + CHK) o1 = o0 + CHK;
    int l = threadIdx.x & 63, j = threadIdx.x >> 6;
    float4 a = make_float4(0.f, 0.f, 0.f, 0.f);
    for (int i = o0 + j; i < o1; i += 4) {
        int r = rows[i];
        float4 v = ((const float4*)(z + (size_t)r * DIMD))[l];
        a.x += v.x; a.y += v.y; a.z += v.z; a.w += v.w;
    }
    part[j][l] = a;
    __syncthreads();
    if (j == 0) {
        float4 bb = part[0][l], c = part[1][l], d = part[2][l], e = part[3][l];
        a = make_float4(bb.x+c.x+d.x+e.x, bb.y+c.y+d.y+e.y,
                        bb.z+c.z+d.z+e.z, bb.w+c.w+d.w+e.w);
        float* p = dw + (size_t)k * DIMD + l * 4;
        if (choffs[k + 1] - choffs[k] == 1) {
            *(float4*)p = a;
        } else {
            atomicAdd(p + 0, a.x); atomicAdd(p + 1, a.y);
            atomicAdd(p + 2, a.z); atomicAdd(p + 3, a.w);
        }
    }
}

// ---------------- cluster-size EMA + perplexity ----------------
__global__ void k_cs(const float* __restrict__ ema_cs,
                     float* __restrict__ cs_io,
                     float* __restrict__ perp) {
    __shared__ float2 red[16];
    int t = threadIdx.x;
    float csd[4];
    float nl = 0.f, el = 0.f;
    #pragma unroll
    for (int i = 0; i < 4; ++i) {
        int k = t * 4 + i;
        float c  = cs_io[k];
        float cd = ema_cs[k] * 0.99f + 0.01f * c;
        csd[i] = cd;
        nl += cd;
        float p = c * (1.0f / 65536.0f);
        el += p * logf(p + 1e-10f);
    }
    #pragma unroll
    for (int off = 32; off; off >>= 1) { nl += __shfl_down(nl, off); el += __shfl_down(el, off); }
    if ((t & 63) == 0) red[t >> 6] = make_float2(nl, el);
    __syncthreads();
    if (t == 0) {
        float n = 0.f, e = 0.f;
        for (int i = 0; i < 16; ++i) { n += red[i].x; e += red[i].y; }
        red[0] = make_float2(n, e);
        perp[0] = expf(-e);
    }
    __syncthreads();
    float n = red[0].x;
    float scale = n / (n + 4096.0f * 1e-5f);
    #pragma unroll
    for (int i = 0; i < 4; ++i)
        cs_io[t * 4 + i] = (csd[i] + 1e-5f) * scale;
}

// ---------------- new_ema_w (in-place over dw) + new_weight ----------------
__global__ void k_emaw(const float* __restrict__ ema_w,
                       const float* __restrict__ cs,
                       float* __restrict__ emaw_io,
                       float* __restrict__ wout) {
    int i = (blockIdx.x * 256 + threadIdx.x) * 4;
    int k = i >> 8;
    float4 dv = *(const float4*)(emaw_io + i);
    float4 ev = *(const float4*)(ema_w + i);
    float c = cs[k];
    float4 ne;
    ne.x = ev.x * 0.99f + 0.01f * dv.x;
    ne.y = ev.y * 0.99f + 0.01f * dv.y;
    ne.z = ev.z * 0.99f + 0.01f * dv.z;
    ne.w = ev.w * 0.99f + 0.01f * dv.w;
    *(float4*)(emaw_io + i) = ne;
    float4 nw = make_float4(ne.x / c, ne.y / c, ne.z / c, ne.w / c);
    *(float4*)(wout + i) = nw;
}

// ---------------- z_q gather + straight-through + loss partial -------------
__global__ void k_zq(const float* __restrict__ z,
                     const float* __restrict__ wnew,
                     const int* __restrict__ idxi,
                     float* __restrict__ zq,
                     float* __restrict__ sqacc) {   // 256 accumulators
    __shared__ float red[4];
    int i = (blockIdx.x * 256 + threadIdx.x) * 4;
    int n = i >> 8;
    int d = i & 255;
    int k = idxi[n];
    float4 wv = *(const float4*)(wnew + (k << 8) + d);
    float4 zv = *(const float4*)(z + i);
    float4 o;
    o.x = zv.x + (wv.x - zv.x);
    o.y = zv.y + (wv.y - zv.y);
    o.z = zv.z + (wv.z - zv.z);
    o.w = zv.w + (wv.w - zv.w);
    *(float4*)(zq + i) = o;
    float dx = wv.x - zv.x, dy = wv.y - zv.y, dz = wv.z - zv.z, dw_ = wv.w - zv.w;
    float s = dx*dx + dy*dy + dz*dz + dw_*dw_;
    #pragma unroll
    for (int off = 32; off; off >>= 1) s += __shfl_down(s, off);
    int lane = threadIdx.x & 63;
    if (lane == 0) red[threadIdx.x >> 6] = s;
    __syncthreads();
    if (threadIdx.x == 0)
        atomicAdd(&sqacc[blockIdx.x & 255], red[0] + red[1] + red[2] + red[3]);
}

__global__ void k_final(const float* __restrict__ sqacc, float* __restrict__ loss) {
    __shared__ float red[4];
    int t = threadIdx.x;
    float s = sqacc[t];
    #pragma unroll
    for (int off = 32; off; off >>= 1) s += __shfl_down(s, off);
    if ((t & 63) == 0) red[t >> 6] = s;
    __syncthreads();
    if (t == 0)
        loss[0] = 1.25f * (red[0] + red[1] + red[2] + red[3]) * (1.0f / 16777216.0f);
}

extern "C" void kernel_launch(void* const* d_in, const int* in_sizes, int n_in,
                              void* d_out, int out_size, void* d_ws, size_t ws_size,
                              hipStream_t stream) {
    const float* z      = (const float*)d_in[0];
    const float* weight = (const float*)d_in[1];
    const float* ema_w  = (const float*)d_in[2];
    const float* ema_cs = (const float*)d_in[3];
    float* out = (float*)d_out;
    float* ws  = (float*)d_ws;

    float* scal = ws + 4096;             // 256 floats
    int*   idxi = (int*)(ws + 8192);     // 65536 ints

    unsigned* zbf    = (unsigned*)(out + O_ZQ);
    uint4*    wsw4   = (uint4*)(out + O_ZQ + OFF_WSW);
    int*      ccnt   = (int*)(out + O_ZQ + OFF_CCNT);
    int*      cids   = (int*)(out + O_ZQ + OFF_CIDS);
    int*      offs   = (int*)(out + O_ZQ + OFF_OFFS);
    int*      cursor = (int*)(out + O_ZQ + OFF_CUR);
    int*      rows   = (int*)(out + O_ZQ + OFF_ROWS);
    unsigned* gmin   = (unsigned*)(out + O_ZQ + OFF_GMIN);
    int*      choffs = (int*)(out + O_ZQ + OFF_CHOF);
    float*    zz     = out + O_EMAW;           // dead before the dw memset
    float*    wwg    = out + O_EMAW + 65536;

    hipMemsetAsync(scal,       0,    256 * 4, stream);
    hipMemsetAsync(out + O_CS, 0,    (size_t)KCB * 4, stream);
    hipMemsetAsync(ccnt,       0,    (size_t)NPTS * 4, stream);
    hipMemsetAsync(gmin,       0xFF, (size_t)NPTS * 4, stream);

    k_prepz  <<<NPTS / 4, 256, 0, stream>>>(z, zbf, zz);
    k_prepw  <<<KCB  / 4, 256, 0, stream>>>(weight, (unsigned*)wsw4, wwg);
    k_pass0  <<<512, 256, 0, stream>>>(zbf, wsw4, wwg, gmin);
    k_pass1  <<<512, 256, 0, stream>>>(zbf, wsw4, wwg, gmin, ccnt, cids);
    k_refine <<<NPTS / 4, 256, 0, stream>>>(z, weight, zz, wwg, ccnt, cids,
                                            out + O_CS, idxi, out + O_IDX);
    // zz/wwg are dead from here; zero the dw region (covers empty clusters
    // and makes the chunk-parallel atomicAdd flush correct).
    hipMemsetAsync(out + O_EMAW, 0, (size_t)KCB * DIMD * 4, stream);
    k_offsets<<<1, 1024, 0, stream>>>(out + O_CS, offs, cursor, choffs);
    k_fill   <<<NPTS / 256, 256, 0, stream>>>(idxi, cursor, rows);
    k_cs     <<<1, 1024, 0, stream>>>(ema_cs, out + O_CS, out + O_PERP);
    k_dw     <<<MAXCHUNKS, 256, 0, stream>>>(z, offs, choffs, rows, out + O_EMAW);
    k_emaw   <<<(KCB * DIMD) / 1024, 256, 0, stream>>>(ema_w, out + O_CS,
                                                       out + O_EMAW, out + O_W);
    k_zq     <<<(NPTS * DIMD) / 1024, 256, 0, stream>>>(z, out + O_W, idxi,
                                                        out + O_ZQ, scal);
    k_final  <<<1, 256, 0, stream>>>(scal, out + O_LOSS);
}

// Round 4
// 494.893 us; speedup vs baseline: 1.5860x; 1.0371x over previous
//
#include <hip/hip_runtime.h>
#include <math.h>

#define NPTS 65536
#define DIMD 256
#define KCB  4096
#define MARGIN 2.0f

// d_out float32 offsets (reference tuple order, flattened)
#define O_ZQ   0
#define O_IDX  16777216
#define O_LOSS 16842752
#define O_PERP 16842753
#define O_CS   16842754
#define O_EMAW 16846850
#define O_W    17895426

// scratch inside d_out O_ZQ region (16,777,216 floats; dead until k_zq):
#define OFF_WSW   8388608      // swizzled w bf16: 256 grp x 8 chunk x 1024 B
#define OFF_CCNT  8912896      // 65536 ints
#define OFF_CIDS  8978432      // 65536 x 16 ints
#define OFF_OFFS  10027008     // 4097 ints
#define OFF_CUR   10031232     // 4096 ints
#define OFF_ROWS  10035328     // 65536 ints
#define OFF_GMIN  10100864     // 65536 uints
#define OFF_CHOF  10166400     // 4097 ints (chunk prefix)
#define OFF_BMIN  10240000     // 65536 x 16 floats (per-row per-256-code-block min)
#define OFF_RL    11288576     // 16 x PADL ints (per-block row lists)
#define OFF_TPRE  12338176     // 17 ints (tile prefix)
// zz -> EMAW region [0,65536); wwg -> EMAW [65536,69632)  (dead before k_dw)

#define CHK 64                 // rows per dw chunk
#define MAXCHUNKS 5120         // 4096 + 65536/64 upper bound
#define PADL 65600             // row-list stride (65536 rounded up + pad room)

// pass0 ring pipeline: 6 LDS slots x 1 group (8 KB), prefetch depth 4.
#define RING 6
#define PFD  4

typedef __attribute__((ext_vector_type(8))) short short8;   // 8 bf16
typedef __attribute__((ext_vector_type(4))) float f32x4;

__device__ __forceinline__ unsigned short f2bf(float f) {   // RNE
    unsigned u = __float_as_uint(f);
    return (unsigned short)((u + 0x7FFF + ((u >> 16) & 1)) >> 16);
}
__device__ __forceinline__ unsigned encf(float f) {         // order-preserving
    unsigned u = __float_as_uint(f);
    return (u >> 31) ? ~u : (u | 0x80000000u);
}
__device__ __forceinline__ float decf(unsigned e) {
    unsigned u = (e & 0x80000000u) ? (e & 0x7fffffffu) : ~e;
    return __uint_as_float(u);
}

// ---------------- z: fp32 -> bf16 row-layout + row sum-of-squares ----------
__global__ void k_prepz(const float* __restrict__ src, unsigned* __restrict__ dst,
                        float* __restrict__ ss) {
    int l   = threadIdx.x & 63;
    int row = blockIdx.x * 4 + (threadIdx.x >> 6);
    float4 v = ((const float4*)(src + (size_t)row * DIMD))[l];
    uint2 pk = make_uint2(f2bf(v.x) | (f2bf(v.y) << 16),
                          f2bf(v.z) | (f2bf(v.w) << 16));
    ((uint2*)dst)[(size_t)row * 64 + l] = pk;
    float s = v.x*v.x + v.y*v.y + v.z*v.z + v.w*v.w;
    #pragma unroll
    for (int off = 32; off; off >>= 1) s += __shfl_down(s, off);
    if (l == 0) ss[row] = s;
}

// ---------------- w: fp32 -> bf16 B-frag-swizzled + sum-of-squares ---------
__global__ void k_prepw(const float* __restrict__ src, unsigned* __restrict__ dst,
                        float* __restrict__ ss) {
    int l   = threadIdx.x & 63;
    int row = blockIdx.x * 4 + (threadIdx.x >> 6);
    float4 v = ((const float4*)(src + (size_t)row * DIMD))[l];
    uint2 pk = make_uint2(f2bf(v.x) | (f2bf(v.y) << 16),
                          f2bf(v.z) | (f2bf(v.w) << 16));
    int g = row >> 4, n16 = row & 15;
    int c = l >> 3, q = (l >> 1) & 3, half = l & 1;
    ((uint2*)dst)[g * 1024 + c * 128 + (q * 16 + n16) * 2 + half] = pk;
    float s = v.x*v.x + v.y*v.y + v.z*v.z + v.w*v.w;
    #pragma unroll
    for (int off = 32; off; off >>= 1) s += __shfl_down(s, off);
    if (l == 0) ss[row] = s;
}

// ---------------- pass 0: per-row bf16-core min + per-block min ------------
// Ring pipeline as before; scan order is 256-code-block aligned (ph0 multiple
// of 16) so a per-block running min fits in 16 regs; at each block boundary
// it is folded into the global min, lane-reduced, and stored to bmin.
__launch_bounds__(256, 2)
__global__ void k_pass0(const unsigned* __restrict__ zbf,
                        const uint4* __restrict__ wsw4,
                        const float* __restrict__ wwg,
                        unsigned* __restrict__ gmin,
                        float* __restrict__ bmin) {
    __shared__ __align__(16) char smem[RING * 8192];
    __shared__ float lds_ww[2048];
    const int t = threadIdx.x, wv = t >> 6, l = t & 63;
    const int q = l >> 4, n16 = l & 15;
    const int rb    = blockIdx.x >> 1;
    const int half  = blockIdx.x & 1;
    const int row0  = rb * 256 + wv * 64;
    const int g0    = half * 128;
    const int ph0   = (blockIdx.x * 48) & 127;   // stagger, multiple of 16

    union U { uint4 u; short8 s; } afr[4][8];
    #pragma unroll
    for (int s = 0; s < 4; ++s) {
        const char* zb = (const char*)zbf + ((size_t)(row0 + s * 16 + n16) << 9) + q * 16;
        #pragma unroll
        for (int c = 0; c < 8; ++c) afr[s][c].u = *(const uint4*)(zb + c * 64);
    }

    auto stage = [&](int buf, int g) {
        const int ga = (ph0 + g) & 127;
        const uint4* srcb = wsw4 + (size_t)(g0 + ga) * 512;
        #pragma unroll
        for (int j = 0; j < 2; ++j) {
            int rrow = j * 4 + wv;
            __builtin_amdgcn_global_load_lds(
                (const __attribute__((address_space(1))) unsigned*)(srcb + rrow * 64 + l),
                (__attribute__((address_space(3))) unsigned*)(&smem[buf * 8192 + rrow * 1024]),
                16, 0, 0);
        }
    };

    for (int i = t; i < 2048; i += 256) lds_ww[i] = wwg[g0 * 16 + i];
    #pragma unroll
    for (int g = 0; g < PFD; ++g) stage(g, g);
    __syncthreads();

    float minv[16], bm[16];
    #pragma unroll
    for (int i = 0; i < 16; ++i) { minv[i] = 3.0e38f; bm[i] = 3.0e38f; }

    int buf = 0, sbuf = PFD;
    #pragma unroll 1
    for (int g = 0; g < 128; ++g) {
        if (g < 128 - PFD) {
            stage(sbuf, g + PFD);
            sbuf = (sbuf == RING - 1) ? 0 : sbuf + 1;
            asm volatile("s_waitcnt vmcnt(8)" ::: "memory");
        } else {
            asm volatile("s_waitcnt vmcnt(0)" ::: "memory");
        }
        __builtin_amdgcn_s_barrier();
        const char* sbase = smem + buf * 8192;
        buf = (buf == RING - 1) ? 0 : buf + 1;
        const int ga = (ph0 + g) & 127;
        f32x4 acc[4];
        #pragma unroll
        for (int s = 0; s < 4; ++s) acc[s] = (f32x4){0.f, 0.f, 0.f, 0.f};
        __builtin_amdgcn_s_setprio(1);
        #pragma unroll
        for (int c = 0; c < 8; ++c) {
            U bf; bf.u = *(const uint4*)(sbase + c * 1024 + (l << 4));
            #pragma unroll
            for (int s = 0; s < 4; ++s)
                acc[s] = __builtin_amdgcn_mfma_f32_16x16x32_bf16(afr[s][c].s, bf.s, acc[s], 0, 0, 0);
        }
        __builtin_amdgcn_s_setprio(0);
        float wwv = lds_ww[ga * 16 + n16];
        #pragma unroll
        for (int s = 0; s < 4; ++s)
            #pragma unroll
            for (int r = 0; r < 4; ++r)
                bm[s*4+r] = fminf(bm[s*4+r], fmaf(-2.f, acc[s][r], wwv));
        if ((g & 15) == 15) {                       // end of a 256-code block
            const int blk = (g0 + ((ph0 + (g & ~15)) & 127)) >> 4;
            #pragma unroll
            for (int i = 0; i < 16; ++i) {
                float m = bm[i];
                minv[i] = fminf(minv[i], m);
                #pragma unroll
                for (int msk = 1; msk < 16; msk <<= 1) m = fminf(m, __shfl_xor(m, msk));
                if (n16 == 0)
                    bmin[(size_t)(row0 + (i >> 2) * 16 + q * 4 + (i & 3)) * 16 + blk] = m;
                bm[i] = 3.0e38f;
            }
        }
    }

    #pragma unroll
    for (int i = 0; i < 16; ++i) {
        float m = minv[i];
        #pragma unroll
        for (int msk = 1; msk < 16; msk <<= 1) m = fminf(m, __shfl_xor(m, msk));
        if (n16 == 0)
            atomicMin(&gmin[row0 + (i >> 2) * 16 + q * 4 + (i & 3)], encf(m));
    }
}

// -------- block-select: per row, append to qualifying blocks' row lists ----
// Exact pruning: block b can contain a margin candidate iff bmin <= gmin+MARGIN.
__global__ void k_bsel(const unsigned* __restrict__ gmin,
                       const float* __restrict__ bmin,
                       int* __restrict__ bcnt, int* __restrict__ rlist) {
    __shared__ int lcnt[16], lbase[16], lcur[16];
    int t = threadIdx.x;
    if (t < 16) { lcnt[t] = 0; lcur[t] = 0; }
    __syncthreads();
    int row = blockIdx.x * 256 + t;
    float thr = decf(gmin[row]) + MARGIN;
    const float* bm = bmin + (size_t)row * 16;
    unsigned qual = 0;
    #pragma unroll
    for (int b = 0; b < 16; ++b)
        if (bm[b] <= thr) { qual |= (1u << b); atomicAdd(&lcnt[b], 1); }
    __syncthreads();
    if (t < 16) lbase[t] = atomicAdd(&bcnt[t], lcnt[t]);
    __syncthreads();
    #pragma unroll
    for (int b = 0; b < 16; ++b)
        if (qual & (1u << b)) {
            int p = atomicAdd(&lcur[b], 1);
            rlist[b * PADL + lbase[b] + p] = row;
        }
}

// -------- pad row lists to 64-row tiles, build tile prefix ----------------
__global__ void k_btile(const int* __restrict__ bcnt, int* __restrict__ rlist,
                        int* __restrict__ tpre) {
    __shared__ int tb[16];
    int t = threadIdx.x;
    if (t < 16) tb[t] = (bcnt[t] + 63) >> 6;
    __syncthreads();
    int b = t >> 4, j = t & 15;
    int n = bcnt[b], e = tb[b] * 64;
    for (int i = n + j; i < e; i += 16) rlist[b * PADL + i] = -1;
    if (t == 0) {
        int s = 0;
        for (int b2 = 0; b2 < 16; ++b2) { tpre[b2] = s; s += tb[b2]; }
        tpre[16] = s;
    }
}

// ---------------- pass 1: emit candidates over pruned tiles ---------------
// Persistent grid; each wave owns tiles of 64 gathered rows x 256 codes.
// B-frags loaded direct (wsw is L2-resident); candidate volume is small so
// global atomics are fine.
__launch_bounds__(256, 2)
__global__ void k_pass1(const unsigned* __restrict__ zbf,
                        const uint4* __restrict__ wsw4,
                        const float* __restrict__ wwg,
                        const unsigned* __restrict__ gmin,
                        const int* __restrict__ tpre,
                        const int* __restrict__ rlist,
                        int* __restrict__ ccnt,
                        int* __restrict__ cids) {
    const int t = threadIdx.x, wv = t >> 6, l = t & 63;
    const int q = l >> 4, n16 = l & 15;
    const int ntiles = tpre[16];
    for (int tile = blockIdx.x * 4 + wv; tile < ntiles; tile += 2048) {
        int b = 0;
        while (b < 15 && tpre[b + 1] <= tile) ++b;
        const int* rl = rlist + b * PADL + (tile - tpre[b]) * 64;

        union U { uint4 u; short8 s; } afr[4][8];
        #pragma unroll
        for (int s = 0; s < 4; ++s) {
            int r = rl[s * 16 + n16];
            int rr = r < 0 ? 0 : r;
            const char* zb = (const char*)zbf + ((size_t)rr << 9) + q * 16;
            #pragma unroll
            for (int c = 0; c < 8; ++c) afr[s][c].u = *(const uint4*)(zb + c * 64);
        }
        float thr[16];
        #pragma unroll
        for (int i = 0; i < 16; ++i) {
            int r = rl[(i >> 2) * 16 + q * 4 + (i & 3)];
            thr[i] = (r < 0) ? -3.0e38f : decf(gmin[r]) + MARGIN;
        }

        #pragma unroll 2
        for (int g = 0; g < 16; ++g) {
            const int gg = b * 16 + g;
            const uint4* wp = wsw4 + (size_t)gg * 512 + l;
            f32x4 acc[4];
            #pragma unroll
            for (int s = 0; s < 4; ++s) acc[s] = (f32x4){0.f, 0.f, 0.f, 0.f};
            #pragma unroll
            for (int c = 0; c < 8; ++c) {
                U bf; bf.u = wp[c * 64];
                #pragma unroll
                for (int s = 0; s < 4; ++s)
                    acc[s] = __builtin_amdgcn_mfma_f32_16x16x32_bf16(afr[s][c].s, bf.s, acc[s], 0, 0, 0);
            }
            float wwv = wwg[gg * 16 + n16];
            #pragma unroll
            for (int s = 0; s < 4; ++s)
                #pragma unroll
                for (int r = 0; r < 4; ++r) {
                    float core = fmaf(-2.f, acc[s][r], wwv);
                    if (core <= thr[s*4+r]) {
                        int row = rl[s * 16 + q * 4 + r];
                        int pos = atomicAdd(&ccnt[row], 1);
                        if (pos < 16) cids[row * 16 + pos] = gg * 16 + n16;
                    }
                }
        }
    }
}

// ---------------- fp32 rescore of candidates ----------------
__global__ void k_refine(const float* __restrict__ z,
                         const float* __restrict__ w,
                         const float* __restrict__ zz,
                         const float* __restrict__ wwg,
                         const int* __restrict__ ccnt,
                         const int* __restrict__ cids,
                         float* __restrict__ counts,
                         int*   __restrict__ idxi,
                         float* __restrict__ idxf) {
    int l   = threadIdx.x & 63;
    int row = blockIdx.x * 4 + (threadIdx.x >> 6);
    int n = ccnt[row]; if (n > 16) n = 16;
    float4 zv = ((const float4*)(z + (size_t)row * DIMD))[l];
    float zzv = zz[row];
    float bd = 3.0e38f; int bi = 0x7fffffff;
    for (int j = 0; j < n; ++j) {
        int k = cids[row * 16 + j];
        float4 wv = ((const float4*)(w + (size_t)k * DIMD))[l];
        float s = zv.x*wv.x + zv.y*wv.y + zv.z*wv.z + zv.w*wv.w;
        #pragma unroll
        for (int off = 32; off; off >>= 1) s += __shfl_xor(s, off);
        float d = (zzv + wwg[k]) - 2.0f * s;
        if (d < bd || (d == bd && k < bi)) { bd = d; bi = k; }
    }
    if (l == 0) {
        idxi[row] = bi;
        idxf[row] = (float)bi;
        atomicAdd(&counts[bi], 1.0f);
    }
}

// ------- exclusive prefix sums: counts -> offs/cursor, ceil(c/CHK) -> choffs
__global__ void k_offsets(const float* __restrict__ counts,
                          int* __restrict__ offs, int* __restrict__ cursor,
                          int* __restrict__ choffs) {
    __shared__ int sc[1024];
    int t = threadIdx.x;
    int c[4]; int s = 0;
    #pragma unroll
    for (int i = 0; i < 4; ++i) { c[i] = (int)counts[t * 4 + i]; s += c[i]; }
    sc[t] = s;
    __syncthreads();
    for (int d = 1; d < 1024; d <<= 1) {
        int v = (t >= d) ? sc[t - d] : 0;
        __syncthreads();
        sc[t] += v;
        __syncthreads();
    }
    int o = sc[t] - s;
    #pragma unroll
    for (int i = 0; i < 4; ++i) { offs[t*4+i] = o; cursor[t*4+i] = o; o += c[i]; }
    if (t == 1023) offs[4096] = sc[1023];
    __syncthreads();

    int ch[4]; int s2 = 0;
    #pragma unroll
    for (int i = 0; i < 4; ++i) { ch[i] = (c[i] + CHK - 1) / CHK; s2 += ch[i]; }
    sc[t] = s2;
    __syncthreads();
    for (int d = 1; d < 1024; d <<= 1) {
        int v = (t >= d) ? sc[t - d] : 0;
        __syncthreads();
        sc[t] += v;
        __syncthreads();
    }
    int o2 = sc[t] - s2;
    #pragma unroll
    for (int i = 0; i < 4; ++i) { choffs[t*4+i] = o2; o2 += ch[i]; }
    if (t == 1023) choffs[4096] = sc[1023];
}

// ---------------- fill inverted row lists ----------------
__global__ void k_fill(const int* __restrict__ idxi, int* __restrict__ cursor,
                       int* __restrict__ rows) {
    int r = blockIdx.x * 256 + threadIdx.x;
    int k = idxi[r];
    int pos = atomicAdd(&cursor[k], 1);
    rows[pos] = r;
}

// ---------------- dw[k,:] += sum of z rows in chunk (chunk-parallel) ------
__global__ void k_dw(const float* __restrict__ z, const int* __restrict__ offs,
                     const int* __restrict__ choffs, const int* __restrict__ rows,
                     float* __restrict__ dw) {
    __shared__ float4 part[4][64];
    int b = blockIdx.x;
    if (b >= choffs[KCB]) return;
    int lo = 0, hi = KCB;
    while (hi - lo > 1) { int mid = (lo + hi) >> 1; if (choffs[mid] <= b) lo = mid; else hi = mid; }
    int k  = lo;
    int ci = b - choffs[k];
    int o0 = offs[k] + ci * CHK;
    int o1 = offs[k + 1]; if (o1 > o0 + CHK) o1 = o0 + CHK;
    int l = threadIdx.x & 63, j = threadIdx.x >> 6;
    float4 a = make_float4(0.f, 0.f, 0.f, 0.f);
    for (int i = o0 + j; i < o1; i += 4) {
        int r = rows[i];
        float4 v = ((const float4*)(z + (size_t)r * DIMD))[l];
        a.x += v.x; a.y += v.y; a.z += v.z; a.w += v.w;
    }
    part[j][l] = a;
    __syncthreads();
    if (j == 0) {
        float4 bb = part[0][l], c = part[1][l], d = part[2][l], e = part[3][l];
        a = make_float4(bb.x+c.x+d.x+e.x, bb.y+c.y+d.y+e.y,
                        bb.z+c.z+d.z+e.z, bb.w+c.w+d.w+e.w);
        float* p = dw + (size_t)k * DIMD + l * 4;
        if (choffs[k + 1] - choffs[k] == 1) {
            *(float4*)p = a;
        } else {
            atomicAdd(p + 0, a.x); atomicAdd(p + 1, a.y);
            atomicAdd(p + 2, a.z); atomicAdd(p + 3, a.w);
        }
    }
}

// ---------------- cluster-size EMA + perplexity ----------------
__global__ void k_cs(const float* __restrict__ ema_cs,
                     float* __restrict__ cs_io,
                     float* __restrict__ perp) {
    __shared__ float2 red[16];
    int t = threadIdx.x;
    float csd[4];
    float nl = 0.f, el = 0.f;
    #pragma unroll
    for (int i = 0; i < 4; ++i) {
        int k = t * 4 + i;
        float c  = cs_io[k];
        float cd = ema_cs[k] * 0.99f + 0.01f * c;
        csd[i] = cd;
        nl += cd;
        float p = c * (1.0f / 65536.0f);
        el += p * logf(p + 1e-10f);
    }
    #pragma unroll
    for (int off = 32; off; off >>= 1) { nl += __shfl_down(nl, off); el += __shfl_down(el, off); }
    if ((t & 63) == 0) red[t >> 6] = make_float2(nl, el);
    __syncthreads();
    if (t == 0) {
        float n = 0.f, e = 0.f;
        for (int i = 0; i < 16; ++i) { n += red[i].x; e += red[i].y; }
        red[0] = make_float2(n, e);
        perp[0] = expf(-e);
    }
    __syncthreads();
    float n = red[0].x;
    float scale = n / (n + 4096.0f * 1e-5f);
    #pragma unroll
    for (int i = 0; i < 4; ++i)
        cs_io[t * 4 + i] = (csd[i] + 1e-5f) * scale;
}

// ---------------- new_ema_w (in-place over dw) + new_weight ----------------
__global__ void k_emaw(const float* __restrict__ ema_w,
                       const float* __restrict__ cs,
                       float* __restrict__ emaw_io,
                       float* __restrict__ wout) {
    int i = (blockIdx.x * 256 + threadIdx.x) * 4;
    int k = i >> 8;
    float4 dv = *(const float4*)(emaw_io + i);
    float4 ev = *(const float4*)(ema_w + i);
    float c = cs[k];
    float4 ne;
    ne.x = ev.x * 0.99f + 0.01f * dv.x;
    ne.y = ev.y * 0.99f + 0.01f * dv.y;
    ne.z = ev.z * 0.99f + 0.01f * dv.z;
    ne.w = ev.w * 0.99f + 0.01f * dv.w;
    *(float4*)(emaw_io + i) = ne;
    float4 nw = make_float4(ne.x / c, ne.y / c, ne.z / c, ne.w / c);
    *(float4*)(wout + i) = nw;
}

// ---------------- z_q gather + straight-through + loss partial -------------
__global__ void k_zq(const float* __restrict__ z,
                     const float* __restrict__ wnew,
                     const int* __restrict__ idxi,
                     float* __restrict__ zq,
                     float* __restrict__ sqacc) {   // 256 accumulators
    __shared__ float red[4];
    int i = (blockIdx.x * 256 + threadIdx.x) * 4;
    int n = i >> 8;
    int d = i & 255;
    int k = idxi[n];
    float4 wv = *(const float4*)(wnew + (k << 8) + d);
    float4 zv = *(const float4*)(z + i);
    float4 o;
    o.x = zv.x + (wv.x - zv.x);
    o.y = zv.y + (wv.y - zv.y);
    o.z = zv.z + (wv.z - zv.z);
    o.w = zv.w + (wv.w - zv.w);
    *(float4*)(zq + i) = o;
    float dx = wv.x - zv.x, dy = wv.y - zv.y, dz = wv.z - zv.z, dw_ = wv.w - zv.w;
    float s = dx*dx + dy*dy + dz*dz + dw_*dw_;
    #pragma unroll
    for (int off = 32; off; off >>= 1) s += __shfl_down(s, off);
    int lane = threadIdx.x & 63;
    if (lane == 0) red[threadIdx.x >> 6] = s;
    __syncthreads();
    if (threadIdx.x == 0)
        atomicAdd(&sqacc[blockIdx.x & 255], red[0] + red[1] + red[2] + red[3]);
}

__global__ void k_final(const float* __restrict__ sqacc, float* __restrict__ loss) {
    __shared__ float red[4];
    int t = threadIdx.x;
    float s = sqacc[t];
    #pragma unroll
    for (int off = 32; off; off >>= 1) s += __shfl_down(s, off);
    if ((t & 63) == 0) red[t >> 6] = s;
    __syncthreads();
    if (t == 0)
        loss[0] = 1.25f * (red[0] + red[1] + red[2] + red[3]) * (1.0f / 16777216.0f);
}

extern "C" void kernel_launch(void* const* d_in, const int* in_sizes, int n_in,
                              void* d_out, int out_size, void* d_ws, size_t ws_size,
                              hipStream_t stream) {
    const float* z      = (const float*)d_in[0];
    const float* weight = (const float*)d_in[1];
    const float* ema_w  = (const float*)d_in[2];
    const float* ema_cs = (const float*)d_in[3];
    float* out = (float*)d_out;
    float* ws  = (float*)d_ws;

    int*   bcnt = (int*)ws;              // 16 ints
    float* scal = ws + 4096;             // 256 floats
    int*   idxi = (int*)(ws + 8192);     // 65536 ints

    unsigned* zbf    = (unsigned*)(out + O_ZQ);
    uint4*    wsw4   = (uint4*)(out + O_ZQ + OFF_WSW);
    int*      ccnt   = (int*)(out + O_ZQ + OFF_CCNT);
    int*      cids   = (int*)(out + O_ZQ + OFF_CIDS);
    int*      offs   = (int*)(out + O_ZQ + OFF_OFFS);
    int*      cursor = (int*)(out + O_ZQ + OFF_CUR);
    int*      rows   = (int*)(out + O_ZQ + OFF_ROWS);
    unsigned* gmin   = (unsigned*)(out + O_ZQ + OFF_GMIN);
    int*      choffs = (int*)(out + O_ZQ + OFF_CHOF);
    float*    bmin   = out + O_ZQ + OFF_BMIN;
    int*      rlist  = (int*)(out + O_ZQ + OFF_RL);
    int*      tpre   = (int*)(out + O_ZQ + OFF_TPRE);
    float*    zz     = out + O_EMAW;           // dead before the dw memset
    float*    wwg    = out + O_EMAW + 65536;

    hipMemsetAsync(bcnt,       0,    16 * 4, stream);
    hipMemsetAsync(scal,       0,    256 * 4, stream);
    hipMemsetAsync(out + O_CS, 0,    (size_t)KCB * 4, stream);
    hipMemsetAsync(ccnt,       0,    (size_t)NPTS * 4, stream);
    hipMemsetAsync(gmin,       0xFF, (size_t)NPTS * 4, stream);

    k_prepz  <<<NPTS / 4, 256, 0, stream>>>(z, zbf, zz);
    k_prepw  <<<KCB  / 4, 256, 0, stream>>>(weight, (unsigned*)wsw4, wwg);
    k_pass0  <<<512, 256, 0, stream>>>(zbf, wsw4, wwg, gmin, bmin);
    k_bsel   <<<NPTS / 256, 256, 0, stream>>>(gmin, bmin, bcnt, rlist);
    k_btile  <<<1, 256, 0, stream>>>(bcnt, rlist, tpre);
    k_pass1  <<<512, 256, 0, stream>>>(zbf, wsw4, wwg, gmin, tpre, rlist,
                                       ccnt, cids);
    k_refine <<<NPTS / 4, 256, 0, stream>>>(z, weight, zz, wwg, ccnt, cids,
                                            out + O_CS, idxi, out + O_IDX);
    // zz/wwg are dead from here; zero the dw region (covers empty clusters
    // and makes the chunk-parallel atomicAdd flush correct).
    hipMemsetAsync(out + O_EMAW, 0, (size_t)KCB * DIMD * 4, stream);
    k_offsets<<<1, 1024, 0, stream>>>(out + O_CS, offs, cursor, choffs);
    k_fill   <<<NPTS / 256, 256, 0, stream>>>(idxi, cursor, rows);
    k_cs     <<<1, 1024, 0, stream>>>(ema_cs, out + O_CS, out + O_PERP);
    k_dw     <<<MAXCHUNKS, 256, 0, stream>>>(z, offs, choffs, rows, out + O_EMAW);
    k_emaw   <<<(KCB * DIMD) / 1024, 256, 0, stream>>>(ema_w, out + O_CS,
                                                       out + O_EMAW, out + O_W);
    k_zq     <<<(NPTS * DIMD) / 1024, 256, 0, stream>>>(z, out + O_W, idxi,
                                                        out + O_ZQ, scal);
    k_final  <<<1, 256, 0, stream>>>(scal, out + O_LOSS);
}

// Round 6
// 441.188 us; speedup vs baseline: 1.7790x; 1.1217x over previous
//
#include <hip/hip_runtime.h>
#include <math.h>

#define NPTS 65536
#define DIMD 256
#define KCB  4096
#define MARGIN 2.0f

// d_out float32 offsets (reference tuple order, flattened)
#define O_ZQ   0
#define O_IDX  16777216
#define O_LOSS 16842752
#define O_PERP 16842753
#define O_CS   16842754
#define O_EMAW 16846850
#define O_W    17895426

// scratch inside d_out O_ZQ region (16,777,216 floats; dead until k_zq):
#define OFF_WSW   8388608      // swizzled w bf16: 256 grp x 8 chunk x 1024 B
#define OFF_CCNT  8912896      // 65536 ints
#define OFF_CIDS  8978432      // 65536 x 16 ints
#define OFF_OFFS  10027008     // 4097 ints
#define OFF_CUR   10031232     // 4096 ints
#define OFF_ROWS  10035328     // 65536 ints
#define OFF_GMIN  10100864     // 65536 uints
#define OFF_CHOF  10166400     // 4097 ints (chunk prefix)
#define OFF_BMIN  10240000     // 65536 x 16 floats (per-row per-256-code-block min)
#define OFF_RL    11288576     // 16 x PADL ints (per-block row lists)
// zz -> EMAW region [0,65536); wwg -> EMAW [65536,69632)  (dead before k_fill zeroes dw)

#define CHK 64                 // rows per dw chunk
#define MAXCHUNKS 5120         // 4096 + 65536/64 upper bound
#define PADL 65600             // row-list stride

// pass0 ring: 4 LDS slots x 2 groups (16 KB each), prefetch depth 2.
// Per slot each wave issues 4 global_load_lds; vmcnt(8) = slots s+1,s+2 in
// flight -> slot s complete (slot-s loads are always the oldest loads).
#define RING0 4
#define NSLOT 64

typedef __attribute__((ext_vector_type(8))) short short8;   // 8 bf16
typedef __attribute__((ext_vector_type(4))) float f32x4;

__device__ __forceinline__ unsigned short f2bf(float f) {   // RNE
    unsigned u = __float_as_uint(f);
    return (unsigned short)((u + 0x7FFF + ((u >> 16) & 1)) >> 16);
}
__device__ __forceinline__ unsigned encf(float f) {         // order-preserving
    unsigned u = __float_as_uint(f);
    return (u >> 31) ? ~u : (u | 0x80000000u);
}
__device__ __forceinline__ float decf(unsigned e) {
    unsigned u = (e & 0x80000000u) ? (e & 0x7fffffffu) : ~e;
    return __uint_as_float(u);
}

// ------- merged prep: z->bf16 rows + zz, w->bf16 swizzle + wwg, + zero-init
__global__ void k_prep(const float* __restrict__ zsrc, const float* __restrict__ wsrc,
                       unsigned* __restrict__ zdst, unsigned* __restrict__ wdst,
                       float* __restrict__ zz, float* __restrict__ wwg,
                       unsigned* __restrict__ gmin, int* __restrict__ ccnt,
                       float* __restrict__ cs, float* __restrict__ scal,
                       int* __restrict__ bcnt) {
    int b = blockIdx.x, t = threadIdx.x;
    int l = t & 63;
    if (b < NPTS / 4) {
        int row = b * 4 + (t >> 6);
        float4 v = ((const float4*)(zsrc + (size_t)row * DIMD))[l];
        uint2 pk = make_uint2(f2bf(v.x) | (f2bf(v.y) << 16),
                              f2bf(v.z) | (f2bf(v.w) << 16));
        ((uint2*)zdst)[(size_t)row * 64 + l] = pk;
        float s = v.x*v.x + v.y*v.y + v.z*v.z + v.w*v.w;
        #pragma unroll
        for (int off = 32; off; off >>= 1) s += __shfl_down(s, off);
        if (l == 0) zz[row] = s;
        if (t < 4) gmin[b * 4 + t] = 0xFFFFFFFFu;
        else if (t < 8) ccnt[b * 4 + (t - 4)] = 0;
    } else {
        int b2 = b - NPTS / 4;
        int row = b2 * 4 + (t >> 6);
        float4 v = ((const float4*)(wsrc + (size_t)row * DIMD))[l];
        uint2 pk = make_uint2(f2bf(v.x) | (f2bf(v.y) << 16),
                              f2bf(v.z) | (f2bf(v.w) << 16));
        int g = row >> 4, n16 = row & 15;
        int c = l >> 3, q = (l >> 1) & 3, half = l & 1;
        ((uint2*)wdst)[g * 1024 + c * 128 + (q * 16 + n16) * 2 + half] = pk;
        float s = v.x*v.x + v.y*v.y + v.z*v.z + v.w*v.w;
        #pragma unroll
        for (int off = 32; off; off >>= 1) s += __shfl_down(s, off);
        if (l == 0) wwg[row] = s;
        if (t < 4) cs[b2 * 4 + t] = 0.f;
        if (b2 == 0) { scal[t] = 0.f; if (t < 16) bcnt[t] = 0; }
    }
}

// ---------------- pass 0: per-row bf16-core min + per-block min ------------
// Ring pipeline, 2 groups (32 codes) per slot, 64 slots. Scan order staggered
// per block in 8-slot (=256-code-block) aligned steps. Per-block running min
// bm folds into minv + bmin store every 8 slots.
__launch_bounds__(256, 2)
__global__ void k_pass0(const unsigned* __restrict__ zbf,
                        const uint4* __restrict__ wsw4,
                        const float* __restrict__ wwg,
                        unsigned* __restrict__ gmin,
                        float* __restrict__ bmin) {
    __shared__ __align__(16) char smem[RING0 * 16384];
    __shared__ float lds_ww[2048];
    const int t = threadIdx.x, wv = t >> 6, l = t & 63;
    const int q = l >> 4, n16 = l & 15;
    const int rb    = blockIdx.x >> 1;
    const int half  = blockIdx.x & 1;
    const int row0  = rb * 256 + wv * 64;
    const int g0    = half * 128;
    const int ph0s  = ((blockIdx.x * 3) & 7) * 8;   // slot stagger, 8-aligned

    union U { uint4 u; short8 s; } afr[4][8];
    #pragma unroll
    for (int s = 0; s < 4; ++s) {
        const char* zb = (const char*)zbf + ((size_t)(row0 + s * 16 + n16) << 9) + q * 16;
        #pragma unroll
        for (int c = 0; c < 8; ++c) afr[s][c].u = *(const uint4*)(zb + c * 64);
    }

    // stage one 16 KB slot (2 groups, 16 rows of 1 KB; 4 rows per wave)
    auto stage = [&](int buf, int s) {
        const int sa = (ph0s + s) & 63;
        const uint4* srcb = wsw4 + (size_t)(g0 + sa * 2) * 512;
        #pragma unroll
        for (int j = 0; j < 4; ++j) {
            int rrow = j * 4 + wv;
            __builtin_amdgcn_global_load_lds(
                (const __attribute__((address_space(1))) unsigned*)(srcb + rrow * 64 + l),
                (__attribute__((address_space(3))) unsigned*)(&smem[buf * 16384 + rrow * 1024]),
                16, 0, 0);
        }
    };

    for (int i = t; i < 2048; i += 256) lds_ww[i] = wwg[g0 * 16 + i];
    stage(0, 0);
    stage(1, 1);
    __syncthreads();                                // full drain once (prologue)

    float minv[16], bm[16];
    #pragma unroll
    for (int i = 0; i < 16; ++i) { minv[i] = 3.0e38f; bm[i] = 3.0e38f; }

    int buf = 0, sbuf = 2;
    #pragma unroll 1
    for (int s = 0; s < NSLOT; ++s) {
        if (s < NSLOT - 2) {
            stage(sbuf, s + 2);
            sbuf = (sbuf + 1) & 3;
            asm volatile("s_waitcnt vmcnt(8)" ::: "memory");
        } else {
            asm volatile("s_waitcnt vmcnt(0)" ::: "memory");
        }
        __builtin_amdgcn_s_barrier();
        const char* sbase = smem + buf * 16384;
        buf = (buf + 1) & 3;
        const int sa = (ph0s + s) & 63;
        #pragma unroll
        for (int g2 = 0; g2 < 2; ++g2) {
            f32x4 acc[4];
            #pragma unroll
            for (int s4 = 0; s4 < 4; ++s4) acc[s4] = (f32x4){0.f, 0.f, 0.f, 0.f};
            __builtin_amdgcn_s_setprio(1);
            #pragma unroll
            for (int c = 0; c < 8; ++c) {
                U bf; bf.u = *(const uint4*)(sbase + g2 * 8192 + c * 1024 + (l << 4));
                #pragma unroll
                for (int s4 = 0; s4 < 4; ++s4)
                    acc[s4] = __builtin_amdgcn_mfma_f32_16x16x32_bf16(afr[s4][c].s, bf.s, acc[s4], 0, 0, 0);
            }
            __builtin_amdgcn_s_setprio(0);
            float wwv = lds_ww[(sa * 2 + g2) * 16 + n16];
            #pragma unroll
            for (int s4 = 0; s4 < 4; ++s4)
                #pragma unroll
                for (int r = 0; r < 4; ++r)
                    bm[s4*4+r] = fminf(bm[s4*4+r], fmaf(-2.f, acc[s4][r], wwv));
        }
        if ((s & 7) == 7) {                         // end of a 256-code block
            const int blk = (g0 >> 4) + (((ph0s + (s & ~7)) & 63) >> 3);
            #pragma unroll
            for (int i = 0; i < 16; ++i) {
                float m = bm[i];
                minv[i] = fminf(minv[i], m);
                #pragma unroll
                for (int msk = 1; msk < 16; msk <<= 1) m = fminf(m, __shfl_xor(m, msk));
                if (n16 == 0)
                    bmin[(size_t)(row0 + (i >> 2) * 16 + q * 4 + (i & 3)) * 16 + blk] = m;
                bm[i] = 3.0e38f;
            }
        }
    }

    #pragma unroll
    for (int i = 0; i < 16; ++i) {
        float m = minv[i];
        #pragma unroll
        for (int msk = 1; msk < 16; msk <<= 1) m = fminf(m, __shfl_xor(m, msk));
        if (n16 == 0)
            atomicMin(&gmin[row0 + (i >> 2) * 16 + q * 4 + (i & 3)], encf(m));
    }
}

// -------- block-select: per row, append to qualifying blocks' row lists ----
__global__ void k_bsel(const unsigned* __restrict__ gmin,
                       const float* __restrict__ bmin,
                       int* __restrict__ bcnt, int* __restrict__ rlist) {
    __shared__ int lcnt[16], lbase[16], lcur[16];
    int t = threadIdx.x;
    if (t < 16) { lcnt[t] = 0; lcur[t] = 0; }
    __syncthreads();
    int row = blockIdx.x * 256 + t;
    float thr = decf(gmin[row]) + MARGIN;
    const float* bm = bmin + (size_t)row * 16;
    unsigned qual = 0;
    #pragma unroll
    for (int b = 0; b < 16; ++b)
        if (bm[b] <= thr) { qual |= (1u << b); atomicAdd(&lcnt[b], 1); }
    __syncthreads();
    if (t < 16) lbase[t] = atomicAdd(&bcnt[t], lcnt[t]);
    __syncthreads();
    #pragma unroll
    for (int b = 0; b < 16; ++b)
        if (qual & (1u << b)) {
            int p = atomicAdd(&lcur[b], 1);
            rlist[b * PADL + lbase[b] + p] = row;
        }
}

// ---------------- pass 1: emit candidates over pruned ragged tiles --------
// Tile prefix derived in-registers from bcnt (no btile kernel, no padding);
// slot idx is valid iff idx < lim.
__launch_bounds__(256, 2)
__global__ void k_pass1(const unsigned* __restrict__ zbf,
                        const uint4* __restrict__ wsw4,
                        const float* __restrict__ wwg,
                        const unsigned* __restrict__ gmin,
                        const int* __restrict__ bcnt,
                        const int* __restrict__ rlist,
                        int* __restrict__ ccnt,
                        int* __restrict__ cids) {
    const int t = threadIdx.x, wv = t >> 6, l = t & 63;
    const int q = l >> 4, n16 = l & 15;
    int bc[16];
    #pragma unroll
    for (int i = 0; i < 16; ++i) bc[i] = bcnt[i];
    int tp[17]; tp[0] = 0;
    #pragma unroll
    for (int i = 0; i < 16; ++i) tp[i + 1] = tp[i] + ((bc[i] + 63) >> 6);
    const int ntiles = tp[16];

    for (int tile = blockIdx.x * 4 + wv; tile < ntiles; tile += 2048) {
        int b = 0, tpb = 0, nb = bc[0];
        #pragma unroll
        for (int i = 1; i < 16; ++i)
            if (tp[i] <= tile) { b = i; tpb = tp[i]; nb = bc[i]; }
        const int lim = nb - (tile - tpb) * 64;
        const int* rl = rlist + b * PADL + (tile - tpb) * 64;

        union U { uint4 u; short8 s; } afr[4][8];
        #pragma unroll
        for (int s = 0; s < 4; ++s) {
            int idx = s * 16 + n16;
            int r = (idx < lim) ? rl[idx] : -1;
            int rr = r < 0 ? 0 : r;
            const char* zb = (const char*)zbf + ((size_t)rr << 9) + q * 16;
            #pragma unroll
            for (int c = 0; c < 8; ++c) afr[s][c].u = *(const uint4*)(zb + c * 64);
        }
        int rowid[16];
        float thr[16];
        #pragma unroll
        for (int i = 0; i < 16; ++i) {
            int idx = (i >> 2) * 16 + q * 4 + (i & 3);
            int r = (idx < lim) ? rl[idx] : -1;
            rowid[i] = r;
            thr[i] = -3.0e38f;
            if (r >= 0) thr[i] = decf(gmin[r]) + MARGIN;
        }

        #pragma unroll 2
        for (int g = 0; g < 16; ++g) {
            const int gg = b * 16 + g;
            const uint4* wp = wsw4 + (size_t)gg * 512 + l;
            f32x4 acc[4];
            #pragma unroll
            for (int s = 0; s < 4; ++s) acc[s] = (f32x4){0.f, 0.f, 0.f, 0.f};
            #pragma unroll
            for (int c = 0; c < 8; ++c) {
                U bf; bf.u = wp[c * 64];
                #pragma unroll
                for (int s = 0; s < 4; ++s)
                    acc[s] = __builtin_amdgcn_mfma_f32_16x16x32_bf16(afr[s][c].s, bf.s, acc[s], 0, 0, 0);
            }
            float wwv = wwg[gg * 16 + n16];
            #pragma unroll
            for (int s = 0; s < 4; ++s)
                #pragma unroll
                for (int r = 0; r < 4; ++r) {
                    float core = fmaf(-2.f, acc[s][r], wwv);
                    if (core <= thr[s*4+r]) {
                        int row = rowid[s * 4 + r];
                        int pos = atomicAdd(&ccnt[row], 1);
                        if (pos < 16) cids[row * 16 + pos] = gg * 16 + n16;
                    }
                }
        }
    }
}

// ---------------- fp32 rescore of candidates ----------------
__global__ void k_refine(const float* __restrict__ z,
                         const float* __restrict__ w,
                         const float* __restrict__ zz,
                         const float* __restrict__ wwg,
                         const int* __restrict__ ccnt,
                         const int* __restrict__ cids,
                         float* __restrict__ counts,
                         int*   __restrict__ idxi,
                         float* __restrict__ idxf) {
    int l   = threadIdx.x & 63;
    int row = blockIdx.x * 4 + (threadIdx.x >> 6);
    int n = ccnt[row]; if (n > 16) n = 16;
    float4 zv = ((const float4*)(z + (size_t)row * DIMD))[l];
    float zzv = zz[row];
    float bd = 3.0e38f; int bi = 0x7fffffff;
    for (int j = 0; j < n; ++j) {
        int k = cids[row * 16 + j];
        float4 wv = ((const float4*)(w + (size_t)k * DIMD))[l];
        float s = zv.x*wv.x + zv.y*wv.y + zv.z*wv.z + zv.w*wv.w;
        #pragma unroll
        for (int off = 32; off; off >>= 1) s += __shfl_xor(s, off);
        float d = (zzv + wwg[k]) - 2.0f * s;
        if (d < bd || (d == bd && k < bi)) { bd = d; bi = k; }
    }
    if (l == 0) {
        idxi[row] = bi;
        idxf[row] = (float)bi;
        atomicAdd(&counts[bi], 1.0f);
    }
}

// ------- merged: prefix sums (offs/cursor/choffs) + cs EMA + perplexity ---
__global__ void k_mid(const float* __restrict__ counts,
                      const float* __restrict__ ema_cs,
                      int* __restrict__ offs, int* __restrict__ cursor,
                      int* __restrict__ choffs,
                      float* __restrict__ cs_io, float* __restrict__ perp) {
    __shared__ int sc[1024];
    __shared__ float2 redf[16];
    int t = threadIdx.x;
    int c[4]; int s = 0;
    #pragma unroll
    for (int i = 0; i < 4; ++i) { c[i] = (int)counts[t * 4 + i]; s += c[i]; }
    sc[t] = s;
    __syncthreads();
    for (int d = 1; d < 1024; d <<= 1) {
        int v = (t >= d) ? sc[t - d] : 0;
        __syncthreads();
        sc[t] += v;
        __syncthreads();
    }
    int o = sc[t] - s;
    #pragma unroll
    for (int i = 0; i < 4; ++i) { offs[t*4+i] = o; cursor[t*4+i] = o; o += c[i]; }
    if (t == 1023) offs[4096] = sc[1023];
    __syncthreads();

    int ch[4]; int s2 = 0;
    #pragma unroll
    for (int i = 0; i < 4; ++i) { ch[i] = (c[i] + CHK - 1) / CHK; s2 += ch[i]; }
    sc[t] = s2;
    __syncthreads();
    for (int d = 1; d < 1024; d <<= 1) {
        int v = (t >= d) ? sc[t - d] : 0;
        __syncthreads();
        sc[t] += v;
        __syncthreads();
    }
    int o2 = sc[t] - s2;
    #pragma unroll
    for (int i = 0; i < 4; ++i) { choffs[t*4+i] = o2; o2 += ch[i]; }
    if (t == 1023) choffs[4096] = sc[1023];
    __syncthreads();

    // cluster-size EMA + perplexity (counts still live in c[])
    float csd[4]; float nl = 0.f, el = 0.f;
    #pragma unroll
    for (int i = 0; i < 4; ++i) {
        float cf = (float)c[i];
        float cd = ema_cs[t * 4 + i] * 0.99f + 0.01f * cf;
        csd[i] = cd;
        nl += cd;
        float p = cf * (1.0f / 65536.0f);
        el += p * logf(p + 1e-10f);
    }
    #pragma unroll
    for (int off = 32; off; off >>= 1) { nl += __shfl_down(nl, off); el += __shfl_down(el, off); }
    if ((t & 63) == 0) redf[t >> 6] = make_float2(nl, el);
    __syncthreads();
    if (t == 0) {
        float n = 0.f, e = 0.f;
        for (int i = 0; i < 16; ++i) { n += redf[i].x; e += redf[i].y; }
        redf[0] = make_float2(n, e);
        perp[0] = expf(-e);
    }
    __syncthreads();
    float n = redf[0].x;
    float scale = n / (n + 4096.0f * 1e-5f);
    #pragma unroll
    for (int i = 0; i < 4; ++i)
        cs_io[t * 4 + i] = (csd[i] + 1e-5f) * scale;
}

// ---------------- fill inverted row lists + zero dw region ----------------
__global__ void k_fill(const int* __restrict__ idxi, int* __restrict__ cursor,
                       int* __restrict__ rows, float* __restrict__ dw) {
    int r = blockIdx.x * 256 + threadIdx.x;
    // zero 16 floats of dw (65536 threads x 16 = 1M floats = KCB*DIMD)
    float4* p = (float4*)(dw + (size_t)r * 16);
    float4 zf = make_float4(0.f, 0.f, 0.f, 0.f);
    p[0] = zf; p[1] = zf; p[2] = zf; p[3] = zf;
    int k = idxi[r];
    int pos = atomicAdd(&cursor[k], 1);
    rows[pos] = r;
}

// ---------------- dw[k,:] += sum of z rows in chunk (chunk-parallel) ------
__global__ void k_dw(const float* __restrict__ z, const int* __restrict__ offs,
                     const int* __restrict__ choffs, const int* __restrict__ rows,
                     float* __restrict__ dw) {
    __shared__ float4 part[4][64];
    int b = blockIdx.x;
    if (b >= choffs[KCB]) return;
    int lo = 0, hi = KCB;
    while (hi - lo > 1) { int mid = (lo + hi) >> 1; if (choffs[mid] <= b) lo = mid; else hi = mid; }
    int k  = lo;
    int ci = b - choffs[k];
    int o0 = offs[k] + ci * CHK;
    int o1 = offs[k + 1]; if (o1 > o0 + CHK) o1 = o0 + CHK;
    int l = threadIdx.x & 63, j = threadIdx.x >> 6;
    float4 a = make_float4(0.f, 0.f, 0.f, 0.f);
    for (int i = o0 + j; i < o1; i += 4) {
        int r = rows[i];
        float4 v = ((const float4*)(z + (size_t)r * DIMD))[l];
        a.x += v.x; a.y += v.y; a.z += v.z; a.w += v.w;
    }
    part[j][l] = a;
    __syncthreads();
    if (j == 0) {
        float4 bb = part[0][l], c = part[1][l], d = part[2][l], e = part[3][l];
        a = make_float4(bb.x+c.x+d.x+e.x, bb.y+c.y+d.y+e.y,
                        bb.z+c.z+d.z+e.z, bb.w+c.w+d.w+e.w);
        float* p = dw + (size_t)k * DIMD + l * 4;
        if (choffs[k + 1] - choffs[k] == 1) {
            *(float4*)p = a;
        } else {
            atomicAdd(p + 0, a.x); atomicAdd(p + 1, a.y);
            atomicAdd(p + 2, a.z); atomicAdd(p + 3, a.w);
        }
    }
}

// ---------------- new_ema_w (in-place over dw) + new_weight ----------------
__global__ void k_emaw(const float* __restrict__ ema_w,
                       const float* __restrict__ cs,
                       float* __restrict__ emaw_io,
                       float* __restrict__ wout) {
    int i = (blockIdx.x * 256 + threadIdx.x) * 4;
    int k = i >> 8;
    float4 dv = *(const float4*)(emaw_io + i);
    float4 ev = *(const float4*)(ema_w + i);
    float c = cs[k];
    float4 ne;
    ne.x = ev.x * 0.99f + 0.01f * dv.x;
    ne.y = ev.y * 0.99f + 0.01f * dv.y;
    ne.z = ev.z * 0.99f + 0.01f * dv.z;
    ne.w = ev.w * 0.99f + 0.01f * dv.w;
    *(float4*)(emaw_io + i) = ne;
    float4 nw = make_float4(ne.x / c, ne.y / c, ne.z / c, ne.w / c);
    *(float4*)(wout + i) = nw;
}

// ---------------- z_q gather + straight-through + loss partial -------------
__global__ void k_zq(const float* __restrict__ z,
                     const float* __restrict__ wnew,
                     const int* __restrict__ idxi,
                     float* __restrict__ zq,
                     float* __restrict__ sqacc) {   // 256 accumulators
    __shared__ float red[4];
    int i = (blockIdx.x * 256 + threadIdx.x) * 4;
    int n = i >> 8;
    int d = i & 255;
    int k = idxi[n];
    float4 wv = *(const float4*)(wnew + (k << 8) + d);
    float4 zv = *(const float4*)(z + i);
    float4 o;
    o.x = zv.x + (wv.x - zv.x);
    o.y = zv.y + (wv.y - zv.y);
    o.z = zv.z + (wv.z - zv.z);
    o.w = zv.w + (wv.w - zv.w);
    *(float4*)(zq + i) = o;
    float dx = wv.x - zv.x, dy = wv.y - zv.y, dz = wv.z - zv.z, dw_ = wv.w - zv.w;
    float s = dx*dx + dy*dy + dz*dz + dw_*dw_;
    #pragma unroll
    for (int off = 32; off; off >>= 1) s += __shfl_down(s, off);
    int lane = threadIdx.x & 63;
    if (lane == 0) red[threadIdx.x >> 6] = s;
    __syncthreads();
    if (threadIdx.x == 0)
        atomicAdd(&sqacc[blockIdx.x & 255], red[0] + red[1] + red[2] + red[3]);
}

__global__ void k_final(const float* __restrict__ sqacc, float* __restrict__ loss) {
    __shared__ float red[4];
    int t = threadIdx.x;
    float s = sqacc[t];
    #pragma unroll
    for (int off = 32; off; off >>= 1) s += __shfl_down(s, off);
    if ((t & 63) == 0) red[t >> 6] = s;
    __syncthreads();
    if (t == 0)
        loss[0] = 1.25f * (red[0] + red[1] + red[2] + red[3]) * (1.0f / 16777216.0f);
}

extern "C" void kernel_launch(void* const* d_in, const int* in_sizes, int n_in,
                              void* d_out, int out_size, void* d_ws, size_t ws_size,
                              hipStream_t stream) {
    const float* z      = (const float*)d_in[0];
    const float* weight = (const float*)d_in[1];
    const float* ema_w  = (const float*)d_in[2];
    const float* ema_cs = (const float*)d_in[3];
    float* out = (float*)d_out;
    float* ws  = (float*)d_ws;

    int*   bcnt = (int*)ws;              // 16 ints
    float* scal = ws + 4096;             // 256 floats
    int*   idxi = (int*)(ws + 8192);     // 65536 ints

    unsigned* zbf    = (unsigned*)(out + O_ZQ);
    uint4*    wsw4   = (uint4*)(out + O_ZQ + OFF_WSW);
    int*      ccnt   = (int*)(out + O_ZQ + OFF_CCNT);
    int*      cids   = (int*)(out + O_ZQ + OFF_CIDS);
    int*      offs   = (int*)(out + O_ZQ + OFF_OFFS);
    int*      cursor = (int*)(out + O_ZQ + OFF_CUR);
    int*      rows   = (int*)(out + O_ZQ + OFF_ROWS);
    unsigned* gmin   = (unsigned*)(out + O_ZQ + OFF_GMIN);
    int*      choffs = (int*)(out + O_ZQ + OFF_CHOF);
    float*    bmin   = out + O_ZQ + OFF_BMIN;
    int*      rlist  = (int*)(out + O_ZQ + OFF_RL);
    float*    zz     = out + O_EMAW;           // dead before k_fill zeroes dw
    float*    wwg    = out + O_EMAW + 65536;

    k_prep   <<<NPTS / 4 + KCB / 4, 256, 0, stream>>>(z, weight, zbf,
                                                      (unsigned*)wsw4, zz, wwg,
                                                      gmin, ccnt, out + O_CS,
                                                      scal, bcnt);
    k_pass0  <<<512, 256, 0, stream>>>(zbf, wsw4, wwg, gmin, bmin);
    k_bsel   <<<NPTS / 256, 256, 0, stream>>>(gmin, bmin, bcnt, rlist);
    k_pass1  <<<512, 256, 0, stream>>>(zbf, wsw4, wwg, gmin, bcnt, rlist,
                                       ccnt, cids);
    k_refine <<<NPTS / 4, 256, 0, stream>>>(z, weight, zz, wwg, ccnt, cids,
                                            out + O_CS, idxi, out + O_IDX);
    k_mid    <<<1, 1024, 0, stream>>>(out + O_CS, ema_cs, offs, cursor, choffs,
                                      out + O_CS, out + O_PERP);
    k_fill   <<<NPTS / 256, 256, 0, stream>>>(idxi, cursor, rows, out + O_EMAW);
    k_dw     <<<MAXCHUNKS, 256, 0, stream>>>(z, offs, choffs, rows, out + O_EMAW);
    k_emaw   <<<(KCB * DIMD) / 1024, 256, 0, stream>>>(ema_w, out + O_CS,
                                                       out + O_EMAW, out + O_W);
    k_zq     <<<(NPTS * DIMD) / 1024, 256, 0, stream>>>(z, out + O_W, idxi,
                                                        out + O_ZQ, scal);
    k_final  <<<1, 256, 0, stream>>>(scal, out + O_LOSS);
}